// Round 12
// baseline (183.664 us; speedup 1.0000x reference)
//
#include <hip/hip_runtime.h>
#include <math.h>

#define BB 2
#define NN 256
#define EE 512
#define PP 256
#define DD 128
#define TT 8
#define KK 8
#define HDIM 256

// workspace offsets (floats)
#define WS_V      0          // B*N*HD = 131072
#define WS_EDGEF  131072     // B*E*D = 131072
#define WS_ETE    262144     // B*E*D = 131072
#define WS_HWT    393216     // B*N*E = 262144
#define WS_K2     655360     // 65536
#define WS_V2     720896     // 65536
#define WS_CNT    786432     // sync counters (ints)
// total ~3.15 MB

__device__ inline unsigned rotl32(unsigned x, int d){ return (x<<d)|(x>>(32-d)); }

__device__ inline float bits_to_gumbel(unsigned bits){
  float f = __uint_as_float((bits>>9)|0x3f800000u) - 1.0f;
  const float minv = 1e-6f;
  const float maxv = 1.0f - 1e-6f;
  float u = f*(maxv-minv) + minv;
  u = fmaxf(minv, u);
  return -logf(-logf(u));
}

__device__ __forceinline__ void f4fma(float4& a, float x, const float4& w){
  a.x += x*w.x; a.y += x*w.y; a.z += x*w.z; a.w += x*w.w;
}

// device-scope grid barrier (all 256 blocks co-resident: 1 block/CU)
__device__ __forceinline__ void grid_sync(int* cnt, int target){
  __syncthreads();
  if (threadIdx.x == 0){
    __threadfence();                       // release our global writes
    atomicAdd(cnt, 1);
    while (__hip_atomic_load(cnt, __ATOMIC_ACQUIRE, __HIP_MEMORY_SCOPE_AGENT) < target){
      __builtin_amdgcn_s_sleep(8);
    }
  }
  __syncthreads();
  __threadfence();                         // acquire: invalidate L1 for all waves
}

// 2 rows x (128->128) dense, 512 threads, 16-way k-split; out may be LDS or global
__device__ __forceinline__ void mlp128x2_512(const float* inA, const float* inB,
      const float* W, const float* bias, float* outA, float* outB, float* part, int t){
  int c=(t&31)*4, ks=t>>5;                 // ks 0..15
  float4 a0=make_float4(0.f,0.f,0.f,0.f), a1=a0;
  #pragma unroll 4
  for (int i=ks*8;i<ks*8+8;i++){
    float4 w = *(const float4*)&W[(size_t)i*DD+c];
    f4fma(a0, inA[i], w); f4fma(a1, inB[i], w);
  }
  *(float4*)&part[(ks*2+0)*DD+c]=a0;
  *(float4*)&part[(ks*2+1)*DD+c]=a1;
  __syncthreads();
  if (t < 256){
    int cc=t&127, r=t>>7;
    float s=0.f;
    #pragma unroll
    for (int k=0;k<16;k++) s+=part[(k*2+r)*DD+cc];
    float val = s + bias[cc];
    if (r==0) outA[cc]=val; else outB[cc]=val;
  }
  __syncthreads();
}

// =========================================================================
// Fused persistent kernel: 256 blocks x 512 threads, 2 grid syncs.
// Stage A: gumbel+c0 (local) | H-compact | incidence | U1 (->LDS) | V | k2/v2
// Stage B: edge pipeline (round-11 structure, U1/etype/g/c0/hcomp local)
// Stage C: agent (msg+q2+attn+final), 2 rows/block
// =========================================================================
__global__ __launch_bounds__(512) void fused_kernel(
    const float* af, const float* at, const float* pf, const float* Hm,
    const float* type_emb,
    const float* wW1, const float* wb1, const float* wW2, const float* wb2,
    const float* dW1, const float* db1, const float* dW2, const float* db2,
    const float* fW1, const float* fb1, const float* fW2, const float* fb2,
    const float* oW1, const float* ob1, const float* oW2, const float* ob2,
    const float* qW,  const float* qb,  const float* kW,  const float* kb,
    const float* vW,  const float* vb,  const float* iqW, const float* iqb,
    const float* ikW, const float* ikb, const float* ivW, const float* ivb,
    const float* opW, const float* opb,
    float* Vg, float* edgef_g, float* ete_g, float* HwT,
    float* k2g, float* v2g, int* cnt,
    float* pnew, float* anew){

  __shared__ float pool[11712];       // 45.75KB multiplexed
  __shared__ float hd4s[4*HDIM];      // 4KB persistent: U1 -> hidden -> U2
  __shared__ int   hcompS[4*256];     // 4KB persistent
  __shared__ int   hcntS[4];
  __shared__ float etloc[4*TT];
  __shared__ float gloc[32];
  __shared__ float wredS[16];
  __shared__ float mredS[4], sinvS[4];
  __shared__ float c0s;
  __shared__ float fdvS[4*KK];

  int blk = blockIdx.x;
  int t = threadIdx.x;                // 512
  int lane = t & 63, wid = t >> 6;    // wid 0..7

  // ================= STAGE A =================
  {
    float* partA = pool;              // 8192
    float* ef    = pool + 8192;       // 512 [4][128]
    float* xsA   = pool + 8704;       // 256 [2][128]
    float* bufB  = pool + 8960;       // 256 [2][128]

    // A1: local gumbel (this block's 32 (e,k) values)
    if (t < 32){
      int j = (blk < 128) ? (blk*32 + t) : ((blk-128)*32 + t);
      const unsigned k0=0u, k1=42u;
      const unsigned ks2 = k0^k1^0x1BD11BDAu;
      unsigned x0 = (unsigned)j, x1 = (unsigned)j + 4096u;
      const int r0_[4]={13,15,26,6}, r1_[4]={17,29,16,24};
      x0 += k0; x1 += k1;
      #pragma unroll
      for(int i=0;i<4;i++){ x0+=x1; x1=rotl32(x1,r0_[i]); x1^=x0; }
      x0+=k1; x1+=ks2+1u;
      #pragma unroll
      for(int i=0;i<4;i++){ x0+=x1; x1=rotl32(x1,r1_[i]); x1^=x0; }
      x0+=ks2; x1+=k0+2u;
      #pragma unroll
      for(int i=0;i<4;i++){ x0+=x1; x1=rotl32(x1,r0_[i]); x1^=x0; }
      x0+=k0; x1+=k1+3u;
      #pragma unroll
      for(int i=0;i<4;i++){ x0+=x1; x1=rotl32(x1,r1_[i]); x1^=x0; }
      x0+=k1; x1+=ks2+4u;
      #pragma unroll
      for(int i=0;i<4;i++){ x0+=x1; x1=rotl32(x1,r0_[i]); x1^=x0; }
      x0+=ks2; x1+=k0+5u;
      gloc[t] = bits_to_gumbel((blk<128)? x0 : x1);
    }
    // A2: c0 partials (t<256)
    if (t < 256){
      float v = fmaxf(wb1 ? 0.f : 0.f, 0.f); // placeholder avoided below
    }
    if (t < 256){
      float v = fmaxf(wb1[t],0.f)*wW2[t];
      #pragma unroll
      for (int s=32;s>0;s>>=1) v += __shfl_xor(v, s, 64);
      if (lane==0) wredS[wid] = v;
    }
    // A3: H compaction (waves 0..3 own edges 0..3 of e0 = blk*4)
    int e0 = blk*4;
    int b  = e0 >> 9;
    if (wid < 4){
      int r = wid;
      const float* Hrow = Hm + (size_t)(e0+r)*NN;
      int base = 0;
      #pragma unroll
      for (int c4=0;c4<4;c4++){
        int n2 = c4*64 + lane;
        bool pred = (Hrow[n2] != 0.f);
        unsigned long long mask = __ballot(pred);
        int off = __popcll(mask & ((1ull<<lane)-1ull));
        if (pred) hcompS[r*256+base+off] = n2;
        base += __popcll(mask);
      }
      if (lane==0) hcntS[r] = base;
    }
    __syncthreads();
    if (t==0) c0s = wredS[0]+wredS[1]+wredS[2]+wredS[3] + wb2[0];
    // A4: incidence -> ef, etloc
    {
      int d = t & 127, r = t >> 7;
      int tot = hcntS[r];
      float a = 0.f, a2 = 0.f;
      for (int i=0;i<tot;i++){
        int n2 = hcompS[r*256+i];
        a += af[((size_t)b*NN+n2)*DD + d];
        if (d < TT) a2 += at[((size_t)b*NN+n2)*TT + d];
      }
      ef[r*DD+d] = a;
      if (d < TT) etloc[r*TT+d] = a2;
    }
    __syncthreads();
    // A5: U1 = ef @ wW1[:D] + wb1 -> hd4s (8-way k-split)
    {
      int c=(t&63)*4, ks=t>>6;
      float4 acc[4];
      #pragma unroll
      for (int r=0;r<4;r++) acc[r]=make_float4(0.f,0.f,0.f,0.f);
      #pragma unroll 4
      for (int i=ks*16; i<ks*16+16; i++){
        float4 w = *(const float4*)&wW1[(size_t)i*HDIM + c];
        #pragma unroll
        for (int r=0;r<4;r++) f4fma(acc[r], ef[r*DD+i], w);
      }
      #pragma unroll
      for (int r=0;r<4;r++) *(float4*)&partA[(ks*4+r)*HDIM + c] = acc[r];
    }
    __syncthreads();
    {
      int h=t&255, rh=t>>8;
      float bv = wb1[h];
      #pragma unroll
      for (int rr=0;rr<2;rr++){
        int r = 2*rh+rr;
        float s=0.f;
        #pragma unroll
        for (int k=0;k<8;k++) s += partA[(k*4+r)*HDIM + h];
        hd4s[r*HDIM+h] = s + bv;
      }
    }
    __syncthreads();
    // A6: V = af @ wW1[D:] (no bias), 2 rows (r0v = blk*2)
    {
      int r0v = blk*2;
      const float* W = wW1 + (size_t)DD*HDIM;
      for (int i=t;i<2*DD;i+=512) xsA[i] = af[(size_t)(r0v+(i>>7))*DD + (i&127)];
      __syncthreads();
      int c=(t&63)*4, ks=t>>6;
      float4 a0=make_float4(0.f,0.f,0.f,0.f), a1=a0;
      #pragma unroll 4
      for (int i=ks*16; i<ks*16+16; i++){
        float4 w = *(const float4*)&W[(size_t)i*HDIM + c];
        f4fma(a0, xsA[i], w); f4fma(a1, xsA[DD+i], w);
      }
      *(float4*)&partA[(ks*2+0)*HDIM + c] = a0;
      *(float4*)&partA[(ks*2+1)*HDIM + c] = a1;
      __syncthreads();
      {
        int h=t&255, r=t>>8;
        float s=0.f;
        #pragma unroll
        for (int k=0;k<8;k++) s += partA[(k*2+r)*HDIM + h];
        Vg[(size_t)(r0v+r)*HDIM + h] = s;
      }
      __syncthreads();
    }
    // A7: k2/v2 chains, 2 rows (r0p = blk*2)
    {
      int r0p = blk*2;
      for (int i=t;i<2*DD;i+=512) xsA[i] = pf[(size_t)(r0p+(i>>7))*DD + (i&127)];
      __syncthreads();
      mlp128x2_512(xsA, xsA+DD, kW, kb, bufB, bufB+DD, partA, t);
      mlp128x2_512(bufB, bufB+DD, ikW, ikb,
                   k2g + (size_t)r0p*DD, k2g + (size_t)(r0p+1)*DD, partA, t);
      mlp128x2_512(xsA, xsA+DD, vW, vb, bufB, bufB+DD, partA, t);
      mlp128x2_512(bufB, bufB+DD, ivW, ivb,
                   v2g + (size_t)r0p*DD, v2g + (size_t)(r0p+1)*DD, partA, t);
    }
  }
  grid_sync(cnt + 0, 256);

  // ================= STAGE B (edge) =================
  {
    float* bufA = pool;               // 8192
    float* w2s  = pool + 8192;        // 2048
    float* w2l  = pool + 10240;       // 256
    float* et4  = pool + 10496;       // 576 [4][144]
    float* redsm= pool + 11072;       // 512

    int e0 = blk*4;
    int b  = e0 >> 9;

    // register preload: wW1 slice for U2
    int cW=(t&63)*4, ksW=t>>6;
    float4 wreg[16];
    #pragma unroll
    for (int i=0;i<16;i++)
      wreg[i] = *(const float4*)&wW1[(size_t)(ksW*16+i)*HDIM + cW];

    if (t < HDIM) w2l[t] = wW2[t];
    for (int i=t;i<HDIM*KK;i+=512) w2s[i] = dW2[i];
    if (t < 32){ int r=t>>3, j=t&7; et4[r*144+DD+j] = etloc[r*TT+j]; }
    __syncthreads();                                      // B1
    // P1: relu-dot L1 partials (h-half split); hd4s holds U1
    {
      int n = t&255, hh = t>>8;
      const float4* Vrow = (const float4*)(Vg + ((size_t)(b*NN)+n)*HDIM);
      float acc[4]={0.f,0.f,0.f,0.f};
      #pragma unroll 4
      for (int ii=hh*32; ii<hh*32+32; ii++){
        float4 v = Vrow[ii];
        float w0=w2l[4*ii+0], w1=w2l[4*ii+1], wc=w2l[4*ii+2], w3=w2l[4*ii+3];
        #pragma unroll
        for (int r=0;r<4;r++){
          acc[r] += fmaxf(hd4s[r*HDIM+4*ii+0]+v.x,0.f)*w0
                  + fmaxf(hd4s[r*HDIM+4*ii+1]+v.y,0.f)*w1
                  + fmaxf(hd4s[r*HDIM+4*ii+2]+v.z,0.f)*wc
                  + fmaxf(hd4s[r*HDIM+4*ii+3]+v.w,0.f)*w3;
        }
      }
      #pragma unroll
      for (int r=0;r<4;r++) bufA[(hh*4+r)*256 + n] = acc[r];
    }
    __syncthreads();                                      // B2
    // P2: wave r: masked softmax for edge r
    if (wid < 4){
      int r = wid;
      float b2v = wb2[0];
      float x[4]; bool msk[4];
      #pragma unroll
      for (int q=0;q<4;q++){
        int n = lane + 64*q;
        msk[q] = (Hm[(size_t)(e0+r)*NN + n] != 0.f);
        x[q] = msk[q] ? (bufA[(0*4+r)*256+n] + bufA[(1*4+r)*256+n] + b2v) : 0.f;
      }
      float m = fmaxf(fmaxf(x[0],x[1]), fmaxf(x[2],x[3]));
      #pragma unroll
      for (int s2=32;s2>0;s2>>=1) m = fmaxf(m, __shfl_xor(m, s2, 64));
      float p[4]; float ss=0.f;
      #pragma unroll
      for (int q=0;q<4;q++){ p[q]=expf(x[q]-m); ss+=p[q]; }
      #pragma unroll
      for (int s2=32;s2>0;s2>>=1) ss += __shfl_xor(ss, s2, 64);
      float inv = 1.f/ss;
      #pragma unroll
      for (int q=0;q<4;q++){
        int n = lane + 64*q;
        bufA[3072 + r*256 + n] = msk[q] ? p[q]*inv : 0.f;
      }
    }
    __syncthreads();                                      // B3
    // P3: aggregate -> et4 + edgef_g
    {
      int d = t & 127, r = t >> 7;
      int tot = hcntS[r];
      float a = 0.f;
      for (int i=0;i<tot;i++){
        int n2 = hcompS[r*256+i];
        a += bufA[3072 + r*256 + n2] * af[((size_t)b*NN+n2)*DD + d];
      }
      et4[r*144+d] = a;
      edgef_g[(size_t)(e0+r)*DD + d] = a;
    }
    __syncthreads();                                      // B4
    // P4: d/f MLP partials (matrix per wave-half)
    {
      int half = t>>8, tt2 = t&255;
      int c=(tt2&63)*4, ks=tt2>>6;
      const float* W = half ? fW1 : dW1;
      float4 acc[4];
      #pragma unroll
      for (int r=0;r<4;r++) acc[r]=make_float4(0.f,0.f,0.f,0.f);
      #pragma unroll 4
      for (int i=ks*34;i<ks*34+34;i++){
        float4 w = *(const float4*)&W[(size_t)i*HDIM+c];
        #pragma unroll
        for (int r=0;r<4;r++) f4fma(acc[r], et4[r*144+i], w);
      }
      #pragma unroll
      for (int r=0;r<4;r++) *(float4*)&bufA[half*4096 + (ks*4+r)*HDIM + c] = acc[r];
    }
    __syncthreads();                                      // B5
    // P5: combine d/f sums; f wave partials -> wredS
    {
      int h=t&255, rh=t>>8;
      float bd = db1[h], bf = fb1[h], fw = fW2[h];
      float val[2];
      #pragma unroll
      for (int rr=0;rr<2;rr++){
        int r = 2*rh+rr;
        float sd=0.f, sf=0.f;
        #pragma unroll
        for (int k=0;k<4;k++){ sd += bufA[(k*4+r)*HDIM+h]; sf += bufA[4096+(k*4+r)*HDIM+h]; }
        hd4s[r*HDIM+h] = fmaxf(sd+bd, 0.f);
        val[rr] = fmaxf(sf+bf, 0.f)*fw;
      }
      #pragma unroll
      for (int s2=32;s2>0;s2>>=1){
        val[0] += __shfl_xor(val[0], s2, 64);
        val[1] += __shfl_xor(val[1], s2, 64);
      }
      if (lane==0){ wredS[wid*2]=val[0]; wredS[wid*2+1]=val[1]; }
    }
    __syncthreads();                                      // B6
    // P6: logits partials
    {
      int r_ = t>>7, rem = t&127, k_ = rem&7, j_ = rem>>3;
      float lp = 0.f;
      #pragma unroll 4
      for (int i=0;i<16;i++){
        int h = j_ + 16*i;
        lp += hd4s[r_*HDIM+h]*w2s[h*KK + k_];
      }
      redsm[t] = lp;
    }
    __syncthreads();                                      // B7
    // P7: wave 0 (32 lanes): facs + logits + gumbel softmax -> fdvS
    if (wid == 0 && lane < 32){
      int r = lane>>3, k = lane&7;
      int base = (r>=2)?4:0, off = r&1;
      float fs = 0.f;
      #pragma unroll
      for (int w=0;w<4;w++) fs += wredS[(base+w)*2 + off];
      float fac = 1.f/(1.f+expf(-(fs+fb2[0])));
      float s = db2[k] + gloc[r*8+k];
      #pragma unroll
      for (int j=0;j<16;j++) s += redsm[r*128 + j*8 + k];
      float z = s*2.0f;                // /tau
      float m = z;
      m = fmaxf(m, __shfl_xor(m, 1, 64));
      m = fmaxf(m, __shfl_xor(m, 2, 64));
      m = fmaxf(m, __shfl_xor(m, 4, 64));
      float pz = expf(z - m);
      float sum = pz;
      sum += __shfl_xor(sum, 1, 64);
      sum += __shfl_xor(sum, 2, 64);
      sum += __shfl_xor(sum, 4, 64);
      fdvS[r*KK+k] = fac * pz / sum;
    }
    __syncthreads();                                      // B8
    // P8: ete
    {
      int d = t&127, r = t>>7;
      float a = 0.f;
      #pragma unroll
      for (int k=0;k<KK;k++) a += fdvS[r*KK+k]*type_emb[(size_t)k*DD + d];
      et4[r*144+d] = a;
      ete_g[(size_t)(e0+r)*DD + d] = a;
    }
    __syncthreads();                                      // B9
    // P9: U2 partials from registers
    {
      float4 acc[4];
      #pragma unroll
      for (int r=0;r<4;r++) acc[r]=make_float4(0.f,0.f,0.f,0.f);
      #pragma unroll
      for (int i=0;i<16;i++){
        int idx = ksW*16 + i;
        #pragma unroll
        for (int r=0;r<4;r++) f4fma(acc[r], et4[r*144+idx], wreg[i]);
      }
      #pragma unroll
      for (int r=0;r<4;r++) *(float4*)&bufA[(ksW*4+r)*HDIM + cW] = acc[r];
    }
    __syncthreads();                                      // B10
    // P10: U2 sums -> hd4s
    {
      int h=t&255, rh=t>>8;
      float bv = wb1[h];
      #pragma unroll
      for (int rr=0;rr<2;rr++){
        int r = 2*rh+rr;
        float s=0.f;
        #pragma unroll
        for (int k=0;k<8;k++) s += bufA[(k*4+r)*HDIM + h];
        hd4s[r*HDIM+h] = s + bv;
      }
    }
    __syncthreads();                                      // B11
    // P11: hw2 relu-dot partials
    {
      int n = t&255, hh = t>>8;
      const float4* Vrow = (const float4*)(Vg + ((size_t)(b*NN)+n)*HDIM);
      float acc[4]={0.f,0.f,0.f,0.f};
      #pragma unroll 4
      for (int ii=hh*32; ii<hh*32+32; ii++){
        float4 v = Vrow[ii];
        float w0=w2l[4*ii+0], w1=w2l[4*ii+1], wc=w2l[4*ii+2], w3=w2l[4*ii+3];
        #pragma unroll
        for (int r=0;r<4;r++){
          acc[r] += fmaxf(hd4s[r*HDIM+4*ii+0]+v.x,0.f)*w0
                  + fmaxf(hd4s[r*HDIM+4*ii+1]+v.y,0.f)*w1
                  + fmaxf(hd4s[r*HDIM+4*ii+2]+v.z,0.f)*wc
                  + fmaxf(hd4s[r*HDIM+4*ii+3]+v.w,0.f)*w3;
        }
      }
      #pragma unroll
      for (int r=0;r<4;r++) bufA[(hh*4+r)*256 + n] = acc[r];
    }
    __syncthreads();                                      // B12
    // P12: wave r: leaky + full softmax; write masked p
    if (wid < 4){
      int r = wid;
      float b2v = wb2[0];
      float c0 = c0s;
      float x[4]; bool msk[4];
      #pragma unroll
      for (int q=0;q<4;q++){
        int n = lane + 64*q;
        msk[q] = (Hm[(size_t)(e0+r)*NN + n] != 0.f);
        float raw = msk[q] ? (bufA[(0*4+r)*256+n] + bufA[(1*4+r)*256+n] + b2v) : c0;
        x[q] = raw>0.f ? raw : 0.01f*raw;
      }
      float m = fmaxf(fmaxf(x[0],x[1]), fmaxf(x[2],x[3]));
      #pragma unroll
      for (int s2=32;s2>0;s2>>=1) m = fmaxf(m, __shfl_xor(m, s2, 64));
      float p[4]; float ss=0.f;
      #pragma unroll
      for (int q=0;q<4;q++){ p[q]=expf(x[q]-m); ss+=p[q]; }
      #pragma unroll
      for (int s2=32;s2>0;s2>>=1) ss += __shfl_xor(ss, s2, 64);
      float inv = 1.f/ss;
      #pragma unroll
      for (int q=0;q<4;q++){
        int n = lane + 64*q;
        bufA[2048 + r*256 + n] = msk[q] ? p[q]*inv : 0.f;
      }
    }
    __syncthreads();                                      // B13
    // P13: assemble float4 -> HwT
    if (t < 256){
      int n = t;
      float4 o4;
      o4.x = bufA[2048 + 0*256 + n];
      o4.y = bufA[2048 + 1*256 + n];
      o4.z = bufA[2048 + 2*256 + n];
      o4.w = bufA[2048 + 3*256 + n];
      int eb = e0 & 511;
      *(float4*)(HwT + ((size_t)(b*NN)+n)*EE + eb) = o4;
    }
  }
  grid_sync(cnt + 1, 256);

  // ================= STAGE C (agent) =================
  {
    int*   ecompC = (int*)pool;            // 1024
    float* wcompC = pool + 1024;           // 1024
    int*   wcntC  = (int*)(pool + 2048);   // 8
    float* agflC  = pool + 2064;           // 1024 [2][512]
    float* partC  = pool + 3088;           // 4096
    float* QsC    = pool + 7184;           // 256 [2][128]
    float* qrC    = pool + 7440;           // 256 [2][128]
    float* attC   = pool + 7696;           // 2056 [2][4][257]
    float* olC    = pool + 9752;           // 256 [2][128]
    float* hidC   = pool + 10008;          // 512 [2][256]

    int n0 = blk*2; int b = n0 >> 8;
    int tt = t & 255, rr = t >> 8;
    int lw = tt >> 6;

    // msg: both rows compact in parallel (row = wave-half)
    {
      int bn = n0 + rr;
      const float* wrow = HwT + (size_t)bn*EE;
      int total = 0;
      #pragma unroll
      for (int p=0;p<2;p++){
        int e = p*256 + tt;
        float w = wrow[e];
        bool pred = (w != 0.f);
        unsigned long long mask = __ballot(pred);
        if (lane==0) wcntC[rr*4+lw] = __popcll(mask);
        int off = __popcll(mask & ((1ull<<lane)-1ull));
        __syncthreads();
        int wb = total;
        for (int ww=0; ww<lw; ww++) wb += wcntC[rr*4+ww];
        if (pred){ ecompC[rr*512+wb+off] = e; wcompC[rr*512+wb+off] = w; }
        total += wcntC[rr*4+0]+wcntC[rr*4+1]+wcntC[rr*4+2]+wcntC[rr*4+3];
        __syncthreads();
      }
      float acc = 0.f;
      const float* srcbase = (tt < DD) ? (edgef_g + (size_t)b*EE*DD + tt)
                                       : (ete_g   + (size_t)b*EE*DD + (tt-DD));
      for (int i=0;i<total;i++){
        acc += wcompC[rr*512+i] * srcbase[(size_t)ecompC[rr*512+i]*DD];
      }
      agflC[rr*512+tt] = acc;
      if (tt < DD) agflC[rr*512+2*DD+tt] = af[(size_t)bn*DD + tt];
    }
    __syncthreads();
    int c=(tt&31)*4, ps=tt>>5;
    // q2 stage1
    {
      float4 a = make_float4(0.f,0.f,0.f,0.f);
      #pragma unroll 4
      for (int i=ps*48;i<ps*48+48;i++){
        float4 w = *(const float4*)&qW[(size_t)i*DD+c];
        f4fma(a, agflC[rr*512+i], w);
      }
      *(float4*)&partC[(rr*8+ps)*DD+c]=a;
    }
    __syncthreads();
    if (t<256){
      int cc=t&127, r=t>>7;
      float s=0.f;
      #pragma unroll
      for (int k=0;k<8;k++) s+=partC[(r*8+k)*DD+cc];
      QsC[r*DD+cc]=s+qb[cc];
    }
    __syncthreads();
    // q2 stage2
    {
      float4 a = make_float4(0.f,0.f,0.f,0.f);
      #pragma unroll 4
      for (int i=ps*16;i<ps*16+16;i++){
        float4 w = *(const float4*)&iqW[(size_t)i*DD+c];
        f4fma(a, QsC[rr*DD+i], w);
      }
      *(float4*)&partC[(rr*8+ps)*DD+c]=a;
    }
    __syncthreads();
    if (t<256){
      int cc=t&127, r=t>>7;
      float s=0.f;
      #pragma unroll
      for (int k=0;k<8;k++) s+=partC[(r*8+k)*DD+cc];
      qrC[r*DD+cc]=s+iqb[cc];
    }
    __syncthreads();
    // attention scores
    const float scale = 0.17677669529663687f;
    {
      const float* krow = k2g + ((size_t)(b*PP) + tt)*DD;
      #pragma unroll
      for (int hh=0;hh<2;hh++){
        int h = rr*2+hh;
        const float4* k4 = (const float4*)(krow + h*32);
        float s0=0.f, s1=0.f;
        #pragma unroll
        for (int jj=0;jj<8;jj++){
          float4 kk = k4[jj];
          s0 += qrC[0*DD+h*32+jj*4+0]*kk.x + qrC[0*DD+h*32+jj*4+1]*kk.y
              + qrC[0*DD+h*32+jj*4+2]*kk.z + qrC[0*DD+h*32+jj*4+3]*kk.w;
          s1 += qrC[1*DD+h*32+jj*4+0]*kk.x + qrC[1*DD+h*32+jj*4+1]*kk.y
              + qrC[1*DD+h*32+jj*4+2]*kk.z + qrC[1*DD+h*32+jj*4+3]*kk.w;
        }
        attC[(0*4+h)*257+tt] = s0*scale;
        attC[(1*4+h)*257+tt] = s1*scale;
      }
    }
    __syncthreads();
    // softmax: 8 waves = 8 (row, head) pairs
    {
      int r = wid>>2, h = wid&3;
      float* a = attC + (r*4+h)*257;
      float v0 = a[lane], v1 = a[lane+64], ve = a[lane+128], v3 = a[lane+192];
      float m = fmaxf(fmaxf(v0,v1), fmaxf(ve,v3));
      #pragma unroll
      for (int s2=32;s2>0;s2>>=1) m = fmaxf(m, __shfl_xor(m, s2, 64));
      float e0_ = expf(v0-m), e1 = expf(v1-m), e2 = expf(ve-m), e3 = expf(v3-m);
      float ss = (e0_+e1)+(e2+e3);
      #pragma unroll
      for (int s2=32;s2>0;s2>>=1) ss += __shfl_xor(ss, s2, 64);
      float inv = 1.f/ss;
      a[lane] = e0_*inv; a[lane+64] = e1*inv;
      a[lane+128] = e2*inv; a[lane+192] = e3*inv;
    }
    __syncthreads();
    // PV
    int h2 = c >> 5;
    {
      float4 acc = make_float4(0.f,0.f,0.f,0.f);
      #pragma unroll 4
      for (int i=0;i<32;i++){
        int p = ps*32+i;
        float4 v = *(const float4*)&v2g[((size_t)(b*PP)+p)*DD + c];
        f4fma(acc, attC[(rr*4+h2)*257+p], v);
      }
      *(float4*)&partC[(rr*8+ps)*DD+c]=acc;
    }
    __syncthreads();
    if (t<256){
      int cc=t&127, r=t>>7;
      float s=0.f;
      #pragma unroll
      for (int k=0;k<8;k++) s+=partC[(r*8+k)*DD+cc];
      olC[r*DD+cc]=s;
    }
    __syncthreads();
    // out-proj -> pnew + LDS
    {
      float4 a2 = make_float4(0.f,0.f,0.f,0.f);
      #pragma unroll 4
      for (int i=ps*16;i<ps*16+16;i++){
        float4 w = *(const float4*)&opW[(size_t)i*DD + c];
        f4fma(a2, olC[rr*DD+i], w);
      }
      *(float4*)&partC[(rr*8+ps)*DD+c]=a2;
    }
    __syncthreads();
    if (t<256){
      int cc=t&127, r=t>>7;
      float s=0.f;
      #pragma unroll
      for (int k=0;k<8;k++) s+=partC[(r*8+k)*DD+cc];
      float pv = s+opb[cc];
      agflC[r*512+3*DD+cc] = pv;
      pnew[(size_t)(n0+r)*DD+cc] = pv;
    }
    __syncthreads();
    // final stage1
    {
      int c1=(t&63)*4, ks1=t>>6;
      float4 acc[2];
      #pragma unroll
      for (int r=0;r<2;r++) acc[r]=make_float4(0.f,0.f,0.f,0.f);
      #pragma unroll 8
      for (int i=ks1*64;i<ks1*64+64;i++){
        float4 w = *(const float4*)&oW1[(size_t)i*HDIM+c1];
        f4fma(acc[0], agflC[0*512+i], w);
        f4fma(acc[1], agflC[1*512+i], w);
      }
      #pragma unroll
      for (int r=0;r<2;r++) *(float4*)&partC[(ks1*2+r)*HDIM+c1]=acc[r];
    }
    __syncthreads();
    {
      int h=t&255, r=t>>8;
      float s=0.f;
      #pragma unroll
      for (int k=0;k<8;k++) s+=partC[(k*2+r)*HDIM+h];
      hidC[r*HDIM+h] = fmaxf(s+ob1[h], 0.f);
    }
    __syncthreads();
    // final stage2
    {
      float4 a2 = make_float4(0.f,0.f,0.f,0.f);
      #pragma unroll 8
      for (int h=ps*32;h<ps*32+32;h++){
        float4 w = *(const float4*)&oW2[(size_t)h*DD+c];
        f4fma(a2, hidC[rr*HDIM+h], w);
      }
      *(float4*)&partC[(rr*8+ps)*DD+c]=a2;
    }
    __syncthreads();
    if (t<256){
      int cc=t&127, r=t>>7;
      float s=0.f;
      #pragma unroll
      for (int k=0;k<8;k++) s+=partC[(r*8+k)*DD+cc];
      anew[(size_t)(n0+r)*DD+cc]=s+ob2[cc];
    }
  }
}

extern "C" void kernel_launch(void* const* d_in, const int* in_sizes, int n_in,
                              void* d_out, int out_size, void* d_ws, size_t ws_size,
                              hipStream_t stream) {
  const float* af       = (const float*)d_in[0];
  const float* at       = (const float*)d_in[1];
  const float* pf       = (const float*)d_in[2];
  const float* Hm       = (const float*)d_in[3];
  const float* type_emb = (const float*)d_in[4];
  const float* w_W1 = (const float*)d_in[5];
  const float* w_b1 = (const float*)d_in[6];
  const float* w_W2 = (const float*)d_in[7];
  const float* w_b2 = (const float*)d_in[8];
  const float* d_W1 = (const float*)d_in[9];
  const float* d_b1 = (const float*)d_in[10];
  const float* d_W2 = (const float*)d_in[11];
  const float* d_b2 = (const float*)d_in[12];
  const float* f_W1 = (const float*)d_in[13];
  const float* f_b1 = (const float*)d_in[14];
  const float* f_W2 = (const float*)d_in[15];
  const float* f_b2 = (const float*)d_in[16];
  const float* o_W1 = (const float*)d_in[17];
  const float* o_b1 = (const float*)d_in[18];
  const float* o_W2 = (const float*)d_in[19];
  const float* o_b2 = (const float*)d_in[20];
  const float* q_W  = (const float*)d_in[21];
  const float* q_b  = (const float*)d_in[22];
  const float* k_W  = (const float*)d_in[23];
  const float* k_b  = (const float*)d_in[24];
  const float* v_W  = (const float*)d_in[25];
  const float* v_b  = (const float*)d_in[26];
  const float* iq_W = (const float*)d_in[27];
  const float* iq_b = (const float*)d_in[28];
  const float* ik_W = (const float*)d_in[29];
  const float* ik_b = (const float*)d_in[30];
  const float* iv_W = (const float*)d_in[31];
  const float* iv_b = (const float*)d_in[32];
  const float* op_W = (const float*)d_in[33];
  const float* op_b = (const float*)d_in[34];

  float* ws   = (float*)d_ws;
  float* out  = (float*)d_out;
  float* anew = out;                 // (B,N,D)
  float* pnew = out + BB*NN*DD;      // (B,N,D)
  int* cnt = (int*)(ws + WS_CNT);

  hipMemsetAsync((void*)cnt, 0, 64, stream);
  fused_kernel<<<256, 512, 0, stream>>>(
      af, at, pf, Hm, type_emb,
      w_W1, w_b1, w_W2, w_b2,
      d_W1, d_b1, d_W2, d_b2,
      f_W1, f_b1, f_W2, f_b2,
      o_W1, o_b1, o_W2, o_b2,
      q_W, q_b, k_W, k_b, v_W, v_b,
      iq_W, iq_b, ik_W, ik_b, iv_W, iv_b,
      op_W, op_b,
      ws+WS_V, ws+WS_EDGEF, ws+WS_ETE, ws+WS_HWT,
      ws+WS_K2, ws+WS_V2, cnt, pnew, anew);
}

// Round 13
// 108.032 us; speedup vs baseline: 1.7001x; 1.7001x over previous
//
#include <hip/hip_runtime.h>
#include <math.h>

#define BB 2
#define NN 256
#define EE 512
#define PP 256
#define DD 128
#define TT 8
#define KK 8
#define HDIM 256

// workspace offsets (floats)
#define WS_G      0          // 8192
#define WS_C0     8192       // 64
#define WS_VT     8256       // B*HD*N = 131072  (V transposed [b][h][n])
#define WS_U1     139328     // B*E*HD = 262144
#define WS_ETYPE  401472     // B*E*T = 8192
#define WS_EDGEF  409664     // B*E*D = 131072
#define WS_ETE    540736     // B*E*D = 131072
#define WS_HWT    671808     // B*N*E = 262144
#define WS_K2T    933952     // B*D*P = 65536  (k2 transposed [b][d][p])
#define WS_V2     999488     // 65536
// total 1065024 floats = 4.26 MB

// prep grid roles
#define PB_GUM 16
#define PB_INC 272    // +256 incidence+U1 blocks (R=4 edges)
#define PB_V   528    // +256 V-MLP blocks (R=2)
#define PB_END 784    // +256 kv blocks (R=2)

__device__ inline unsigned rotl32(unsigned x, int d){ return (x<<d)|(x>>(32-d)); }

__device__ inline float bits_to_gumbel(unsigned bits){
  float f = __uint_as_float((bits>>9)|0x3f800000u) - 1.0f;
  const float minv = 1e-6f;
  const float maxv = 1.0f - 1e-6f;
  float u = f*(maxv-minv) + minv;
  u = fmaxf(minv, u);
  return -logf(-logf(u));
}

__device__ __forceinline__ void f4fma(float4& a, float x, const float4& w){
  a.x += x*w.x; a.y += x*w.y; a.z += x*w.z; a.w += x*w.w;
}

__device__ __forceinline__ void block_reduce2_sum(float v[2], float* wred){
  int lane = threadIdx.x & 63, wid = threadIdx.x >> 6;
  #pragma unroll
  for (int s=32;s>0;s>>=1){
    #pragma unroll
    for (int r=0;r<2;r++){ v[r] += __shfl_xor(v[r], s, 64); }
  }
  if (lane==0){
    #pragma unroll
    for (int r=0;r<2;r++) wred[wid*2+r]=v[r];
  }
  __syncthreads();
  #pragma unroll
  for (int r=0;r<2;r++)
    v[r] = (wred[0*2+r]+wred[1*2+r]) + (wred[2*2+r]+wred[3*2+r]);
  __syncthreads();
}

// ---- 2 rows x (128->128) dense layer, float4 + 8-way k-split (256 t) ----
__device__ __forceinline__ void mlp128_lds2(const float (*in)[DD], const float* W, const float* bias,
                                            float (*outl)[DD], float* part, int t){
  int c=(t&31)*4, ks=t>>5;
  float4 a[2];
  #pragma unroll
  for (int r=0;r<2;r++) a[r]=make_float4(0.f,0.f,0.f,0.f);
  #pragma unroll 4
  for (int i=ks*16;i<ks*16+16;i++){
    float4 w = *(const float4*)&W[(size_t)i*DD+c];
    #pragma unroll
    for (int r=0;r<2;r++) f4fma(a[r], in[r][i], w);
  }
  #pragma unroll
  for (int r=0;r<2;r++) *(float4*)&part[(ks*2+r)*DD+c]=a[r];
  __syncthreads();
  int cc=t&127, r=t>>7;
  {
    float s=0.f;
    #pragma unroll
    for (int k2=0;k2<8;k2++) s+=part[(k2*2+r)*DD+cc];
    outl[r][cc]=s+bias[cc];
  }
  __syncthreads();
}

__device__ __forceinline__ void mlp128_glob2(const float (*in)[DD], const float* W, const float* bias,
                                             float* dst, int r0, float* part, int t){
  int c=(t&31)*4, ks=t>>5;
  float4 a[2];
  #pragma unroll
  for (int r=0;r<2;r++) a[r]=make_float4(0.f,0.f,0.f,0.f);
  #pragma unroll 4
  for (int i=ks*16;i<ks*16+16;i++){
    float4 w = *(const float4*)&W[(size_t)i*DD+c];
    #pragma unroll
    for (int r=0;r<2;r++) f4fma(a[r], in[r][i], w);
  }
  #pragma unroll
  for (int r=0;r<2;r++) *(float4*)&part[(ks*2+r)*DD+c]=a[r];
  __syncthreads();
  int cc=t&127, r=t>>7;
  {
    float s=0.f;
    #pragma unroll
    for (int k2=0;k2<8;k2++) s+=part[(k2*2+r)*DD+cc];
    dst[(size_t)(r0+r)*DD+cc]=s+bias[cc];
  }
  __syncthreads();
}

// transposed-output variant: dstT[b][d][p], rv = r0+r, b=rv>>8, p=rv&255
__device__ __forceinline__ void mlp128_glob2T(const float (*in)[DD], const float* W, const float* bias,
                                              float* dstT, int r0, float* part, int t){
  int c=(t&31)*4, ks=t>>5;
  float4 a[2];
  #pragma unroll
  for (int r=0;r<2;r++) a[r]=make_float4(0.f,0.f,0.f,0.f);
  #pragma unroll 4
  for (int i=ks*16;i<ks*16+16;i++){
    float4 w = *(const float4*)&W[(size_t)i*DD+c];
    #pragma unroll
    for (int r=0;r<2;r++) f4fma(a[r], in[r][i], w);
  }
  #pragma unroll
  for (int r=0;r<2;r++) *(float4*)&part[(ks*2+r)*DD+c]=a[r];
  __syncthreads();
  int cc=t&127, r=t>>7;
  {
    float s=0.f;
    #pragma unroll
    for (int k2=0;k2<8;k2++) s+=part[(k2*2+r)*DD+cc];
    int rv = r0+r;
    dstT[((size_t)(rv>>8)*DD + cc)*PP + (rv&255)] = s+bias[cc];
  }
  __syncthreads();
}

// =========================================================================
// K1 prep: gumbel+c0 | incidence+U1 (R=4) | V-MLP->VT (R=2) | k2T/v2 (R=2)
// =========================================================================
__global__ void prep_kernel(float* g, float* c0, const float* w_b1,
                            const float* w_W2, const float* w_b2,
                            const float* Hm, const float* af, const float* at,
                            const float* wW1, const float* wb1,
                            float* U1g, float* etype_g, float* VTg,
                            const float* pf,
                            const float* kW, const float* kb, const float* ikW, const float* ikb,
                            const float* vW, const float* vb, const float* ivW, const float* ivb,
                            float* k2T, float* v2){
  __shared__ float part[4096];       // 16KB
  __shared__ float wred[16];
  __shared__ int   hcomp[4*256];     // 4KB
  __shared__ int   hcnt[4];
  __shared__ float ef[4][DD];        // 2KB
  __shared__ float xs[2][DD];
  __shared__ float bufB[2][DD];
  int blk = blockIdx.x;
  int t = threadIdx.x;               // 256
  int lane = t & 63, wid = t >> 6;

  if (blk < PB_GUM){
    int j = blk*256 + t;
    {
      const unsigned k0=0u, k1=42u;
      const unsigned ks2 = k0^k1^0x1BD11BDAu;
      unsigned x0 = (unsigned)j, x1 = (unsigned)j + 4096u;
      const int r0_[4]={13,15,26,6}, r1_[4]={17,29,16,24};
      x0 += k0; x1 += k1;
      #pragma unroll
      for(int i=0;i<4;i++){ x0+=x1; x1=rotl32(x1,r0_[i]); x1^=x0; }
      x0+=k1; x1+=ks2+1u;
      #pragma unroll
      for(int i=0;i<4;i++){ x0+=x1; x1=rotl32(x1,r1_[i]); x1^=x0; }
      x0+=ks2; x1+=k0+2u;
      #pragma unroll
      for(int i=0;i<4;i++){ x0+=x1; x1=rotl32(x1,r0_[i]); x1^=x0; }
      x0+=k0; x1+=k1+3u;
      #pragma unroll
      for(int i=0;i<4;i++){ x0+=x1; x1=rotl32(x1,r1_[i]); x1^=x0; }
      x0+=k1; x1+=ks2+4u;
      #pragma unroll
      for(int i=0;i<4;i++){ x0+=x1; x1=rotl32(x1,r0_[i]); x1^=x0; }
      x0+=ks2; x1+=k0+5u;
      g[j]      = bits_to_gumbel(x0);
      g[j+4096] = bits_to_gumbel(x1);
    }
    if (blk == 0){
      float v4[2];
      v4[0] = fmaxf(w_b1[t],0.f)*w_W2[t]; v4[1]=0.f;
      block_reduce2_sum(v4, wred);
      if (t==0) c0[0] = v4[0] + w_b2[0];
    }
  } else if (blk < PB_INC){
    // ---- incidence + U1, R=4 edges ----
    int e0 = (blk - PB_GUM)*4;
    int b = e0 >> 9;
    {
      int r = wid;
      const float* Hrow = Hm + (size_t)(e0+r)*NN;
      int base = 0;
      #pragma unroll
      for (int c4=0;c4<4;c4++){
        int n2 = c4*64 + lane;
        bool pred = (Hrow[n2] != 0.f);
        unsigned long long mask = __ballot(pred);
        int off = __popcll(mask & ((1ull<<lane)-1ull));
        if (pred) hcomp[r*256+base+off] = n2;
        base += __popcll(mask);
      }
      if (lane==0) hcnt[r] = base;
    }
    __syncthreads();
    {
      int d = t & 127, eh = t >> 7;
      #pragma unroll
      for (int rr=0;rr<2;rr++){
        int r = eh*2 + rr;
        int tot = hcnt[r];
        float a = 0.f, a2 = 0.f;
        for (int i=0;i<tot;i++){
          int n2 = hcomp[r*256+i];
          a += af[((size_t)b*NN+n2)*DD + d];
          if (d < TT) a2 += at[((size_t)b*NN+n2)*TT + d];
        }
        ef[r][d] = a;
        if (d < TT) etype_g[(size_t)(e0+r)*TT + d] = a2;
      }
    }
    __syncthreads();
    {
      int c = (t&63)*4, ks = t>>6;
      float4 acc[4];
      #pragma unroll
      for (int r=0;r<4;r++) acc[r]=make_float4(0.f,0.f,0.f,0.f);
      #pragma unroll 8
      for (int i=ks*32; i<ks*32+32; i++){
        float4 w = *(const float4*)&wW1[(size_t)i*HDIM + c];
        #pragma unroll
        for (int r=0;r<4;r++) f4fma(acc[r], ef[r][i], w);
      }
      #pragma unroll
      for (int r=0;r<4;r++) *(float4*)&part[(ks*4+r)*HDIM + c] = acc[r];
    }
    __syncthreads();
    {
      float bv = wb1[t];
      #pragma unroll
      for (int r=0;r<4;r++){
        float s = (part[(0*4+r)*HDIM+t] + part[(1*4+r)*HDIM+t])
                + (part[(2*4+r)*HDIM+t] + part[(3*4+r)*HDIM+t]);
        U1g[(size_t)(e0+r)*HDIM + t] = s + bv;
      }
    }
  } else if (blk < PB_V){
    // ---- V = af @ wW1[D:] (no bias), R=2 rows -> VT[b][h][n] ----
    int r0 = (blk - PB_INC)*2;
    const float* W = wW1 + (size_t)DD*HDIM;
    for (int i=t;i<2*DD;i+=256) xs[i>>7][i&127] = af[(size_t)(r0+(i>>7))*DD + (i&127)];
    __syncthreads();
    int c = (t&63)*4, ks = t>>6;
    float4 acc[2];
    #pragma unroll
    for (int r=0;r<2;r++) acc[r]=make_float4(0.f,0.f,0.f,0.f);
    #pragma unroll 8
    for (int i=ks*32; i<ks*32+32; i++){
      float4 w = *(const float4*)&W[(size_t)i*HDIM + c];
      #pragma unroll
      for (int r=0;r<2;r++) f4fma(acc[r], xs[r][i], w);
    }
    #pragma unroll
    for (int r=0;r<2;r++) *(float4*)&part[(ks*2+r)*HDIM + c] = acc[r];
    __syncthreads();
    #pragma unroll
    for (int r=0;r<2;r++){
      float s = (part[(0*2+r)*HDIM+t] + part[(1*2+r)*HDIM+t])
              + (part[(2*2+r)*HDIM+t] + part[(3*2+r)*HDIM+t]);
      int rv = r0+r;
      VTg[((size_t)(rv>>8)*HDIM + t)*NN + (rv&255)] = s;
    }
  } else {
    // ---- k2T/v2 chains from pf, R=2 rows ----
    int r0 = (blk - PB_V)*2;
    for (int i=t;i<2*DD;i+=256) xs[i>>7][i&127] = pf[(size_t)(r0+(i>>7))*DD + (i&127)];
    __syncthreads();
    mlp128_lds2  (xs, kW, kb, bufB, part, t);
    mlp128_glob2T(bufB, ikW, ikb, k2T, r0, part, t);
    mlp128_lds2  (xs, vW, vb, bufB, part, t);
    mlp128_glob2 (bufB, ivW, ivb, v2, r0, part, t);
  }
}

// =========================================================================
// K2 edge: R=4, 256 blocks, 512 threads; VT coalesced relu-dots
// =========================================================================
__global__ __launch_bounds__(512) void edge_kernel(
                            const float* Hm, const float* af,
                            const float* VT, const float* U1g, const float* etype_g,
                            const float* wW1, const float* wb1, const float* wW2, const float* wb2,
                            const float* dW1, const float* db1, const float* dW2, const float* db2,
                            const float* fW1, const float* fb1, const float* fW2, const float* fb2,
                            const float* type_emb, const float* g, const float* c0p,
                            float* edgef_g, float* ete_g, float* HwT){
  __shared__ float bufA[8192];        // 32KB multiplexed
  __shared__ float w2s[HDIM*KK];      // 8KB dW2
  __shared__ float w2l[HDIM];         // wW2
  __shared__ float et4[4][144];       // etype -> edgef -> ete
  __shared__ float hd4[4][HDIM];      // U1 -> relu-hidden -> U2
  __shared__ float redsm[512];
  __shared__ float wred[16];
  __shared__ float fdv[4][KK];
  __shared__ int   hcnt[4];
  __shared__ int   hcomp[4*256];      // 4KB

  int e0 = blockIdx.x*4;
  int b  = e0 >> 9;
  int t  = threadIdx.x;               // 512
  int lane = t & 63, wid = t >> 6;    // wid 0..7

  // register preload: wW1 slice for U2
  int cW=(t&63)*4, ksW=t>>6;
  float4 wreg[16];
  #pragma unroll
  for (int i=0;i<16;i++)
    wreg[i] = *(const float4*)&wW1[(size_t)(ksW*16+i)*HDIM + cW];

  if (t < HDIM) w2l[t] = wW2[t];
  for (int i=t;i<HDIM*KK;i+=512) w2s[i] = dW2[i];
  {
    int h=t&255, rh=t>>8;
    #pragma unroll
    for (int rr=0;rr<2;rr++){
      int r = 2*rh+rr;
      hd4[r][h] = U1g[(size_t)(e0+r)*HDIM + h];
    }
  }
  if (t < 32){ int r=t>>3, j=t&7; et4[r][DD+j] = etype_g[(size_t)(e0+r)*TT + j]; }
  if (wid < 4){
    int r = wid;
    const float* Hrow = Hm + (size_t)(e0+r)*NN;
    int base = 0;
    #pragma unroll
    for (int c4=0;c4<4;c4++){
      int n2 = c4*64 + lane;
      bool pred = (Hrow[n2] != 0.f);
      unsigned long long mask = __ballot(pred);
      int off = __popcll(mask & ((1ull<<lane)-1ull));
      if (pred) hcomp[r*256+base+off] = n2;
      base += __popcll(mask);
    }
    if (lane==0) hcnt[r] = base;
  }
  __syncthreads();                                        // B1
  // P1: relu-dot L1 partials (h-half split), VT coalesced
  {
    int n = t&255, hh = t>>8;
    const float* VTb = VT + (size_t)b*HDIM*NN + n;
    float acc[4]={0.f,0.f,0.f,0.f};
    #pragma unroll 8
    for (int h=hh*128; h<hh*128+128; h++){
      float v = VTb[(size_t)h*NN];
      float w = w2l[h];
      #pragma unroll
      for (int r=0;r<4;r++)
        acc[r] += fmaxf(hd4[r][h]+v,0.f)*w;
    }
    #pragma unroll
    for (int r=0;r<4;r++) bufA[(hh*4+r)*256 + n] = acc[r];
  }
  __syncthreads();                                        // B2
  // P2: wave r does full masked softmax for edge r; writes p
  if (wid < 4){
    int r = wid;
    float b2v = wb2[0];
    float x[4]; bool msk[4];
    #pragma unroll
    for (int q=0;q<4;q++){
      int n = lane + 64*q;
      msk[q] = (Hm[(size_t)(e0+r)*NN + n] != 0.f);
      x[q] = msk[q] ? (bufA[(0*4+r)*256+n] + bufA[(1*4+r)*256+n] + b2v) : 0.f;
    }
    float m = fmaxf(fmaxf(x[0],x[1]), fmaxf(x[2],x[3]));
    #pragma unroll
    for (int s2=32;s2>0;s2>>=1) m = fmaxf(m, __shfl_xor(m, s2, 64));
    float p[4]; float ss=0.f;
    #pragma unroll
    for (int q=0;q<4;q++){ p[q]=expf(x[q]-m); ss+=p[q]; }
    #pragma unroll
    for (int s2=32;s2>0;s2>>=1) ss += __shfl_xor(ss, s2, 64);
    float inv = 1.f/ss;
    #pragma unroll
    for (int q=0;q<4;q++){
      int n = lane + 64*q;
      bufA[3072 + r*256 + n] = msk[q] ? p[q]*inv : 0.f;
    }
  }
  __syncthreads();                                        // B3
  // P3: aggregate -> et4 + edgef_g
  {
    int d = t & 127, r = t >> 7;
    int tot = hcnt[r];
    float a = 0.f;
    for (int i=0;i<tot;i++){
      int n2 = hcomp[r*256+i];
      a += bufA[3072 + r*256 + n2] * af[((size_t)b*NN+n2)*DD + d];
    }
    et4[r][d] = a;
    edgef_g[(size_t)(e0+r)*DD + d] = a;
  }
  __syncthreads();                                        // B4
  // P4: d/f MLP partials (matrix per wave-half)
  {
    int half = t>>8, tt = t&255;
    int c=(tt&63)*4, ks=tt>>6;
    const float* W = half ? fW1 : dW1;
    float4 acc[4];
    #pragma unroll
    for (int r=0;r<4;r++) acc[r]=make_float4(0.f,0.f,0.f,0.f);
    #pragma unroll 4
    for (int i=ks*34;i<ks*34+34;i++){
      float4 w = *(const float4*)&W[(size_t)i*HDIM+c];
      #pragma unroll
      for (int r=0;r<4;r++) f4fma(acc[r], et4[r][i], w);
    }
    #pragma unroll
    for (int r=0;r<4;r++) *(float4*)&bufA[half*4096 + (ks*4+r)*HDIM + c] = acc[r];
  }
  __syncthreads();                                        // B5
  // P5: combine d/f sums; f-sum wave partials -> wred
  {
    int h=t&255, rh=t>>8;
    float bd = db1[h], bf = fb1[h], fw = fW2[h];
    float val[2];
    #pragma unroll
    for (int rr=0;rr<2;rr++){
      int r = 2*rh+rr;
      float sd=0.f, sf=0.f;
      #pragma unroll
      for (int k=0;k<4;k++){ sd += bufA[(k*4+r)*HDIM+h]; sf += bufA[4096+(k*4+r)*HDIM+h]; }
      hd4[r][h] = fmaxf(sd+bd, 0.f);
      val[rr] = fmaxf(sf+bf, 0.f)*fw;
    }
    #pragma unroll
    for (int s2=32;s2>0;s2>>=1){
      val[0] += __shfl_xor(val[0], s2, 64);
      val[1] += __shfl_xor(val[1], s2, 64);
    }
    if (lane==0){ wred[wid*2]=val[0]; wred[wid*2+1]=val[1]; }
  }
  __syncthreads();                                        // B6
  // P6: logits partials
  {
    int r_ = t>>7, rem = t&127, k_ = rem&7, j_ = rem>>3;
    float lp = 0.f;
    #pragma unroll 4
    for (int i=0;i<16;i++){
      int h = j_ + 16*i;
      lp += hd4[r_][h]*w2s[h*KK + k_];
    }
    redsm[t] = lp;
  }
  __syncthreads();                                        // B7
  // P7: wave 0 (32 lanes): facs + logits-combine + gumbel softmax -> fdv
  if (wid == 0 && lane < 32){
    int r = lane>>3, k = lane&7;
    int base = (r>=2)?4:0, off = r&1;
    float fs = 0.f;
    #pragma unroll
    for (int w=0;w<4;w++) fs += wred[(base+w)*2 + off];
    float fac = 1.f/(1.f+expf(-(fs+fb2[0])));
    float s = db2[k] + g[(size_t)(e0+r)*KK + k];
    #pragma unroll
    for (int j=0;j<16;j++) s += redsm[r*128 + j*8 + k];
    float z = s*2.0f;                 // /tau
    float m = z;
    m = fmaxf(m, __shfl_xor(m, 1, 64));
    m = fmaxf(m, __shfl_xor(m, 2, 64));
    m = fmaxf(m, __shfl_xor(m, 4, 64));
    float pz = expf(z - m);
    float sum = pz;
    sum += __shfl_xor(sum, 1, 64);
    sum += __shfl_xor(sum, 2, 64);
    sum += __shfl_xor(sum, 4, 64);
    fdv[r][k] = fac * pz / sum;
  }
  __syncthreads();                                        // B8
  // P8: ete
  {
    int d = t&127, r = t>>7;
    float a = 0.f;
    #pragma unroll
    for (int k=0;k<KK;k++) a += fdv[r][k]*type_emb[(size_t)k*DD + d];
    et4[r][d] = a;
    ete_g[(size_t)(e0+r)*DD + d] = a;
  }
  __syncthreads();                                        // B9
  // P9: U2 partials from registers
  {
    float4 acc[4];
    #pragma unroll
    for (int r=0;r<4;r++) acc[r]=make_float4(0.f,0.f,0.f,0.f);
    #pragma unroll
    for (int i=0;i<16;i++){
      int idx = ksW*16 + i;
      #pragma unroll
      for (int r=0;r<4;r++) f4fma(acc[r], et4[r][idx], wreg[i]);
    }
    #pragma unroll
    for (int r=0;r<4;r++) *(float4*)&bufA[(ksW*4+r)*HDIM + cW] = acc[r];
  }
  __syncthreads();                                        // B10
  // P10: U2 sums -> hd4
  {
    int h=t&255, rh=t>>8;
    float bv = wb1[h];
    #pragma unroll
    for (int rr=0;rr<2;rr++){
      int r = 2*rh+rr;
      float s=0.f;
      #pragma unroll
      for (int k=0;k<8;k++) s += bufA[(k*4+r)*HDIM + h];
      hd4[r][h] = s + bv;
    }
  }
  __syncthreads();                                        // B11
  // P11: hw2 relu-dot partials, VT coalesced
  {
    int n = t&255, hh = t>>8;
    const float* VTb = VT + (size_t)b*HDIM*NN + n;
    float acc[4]={0.f,0.f,0.f,0.f};
    #pragma unroll 8
    for (int h=hh*128; h<hh*128+128; h++){
      float v = VTb[(size_t)h*NN];
      float w = w2l[h];
      #pragma unroll
      for (int r=0;r<4;r++)
        acc[r] += fmaxf(hd4[r][h]+v,0.f)*w;
    }
    #pragma unroll
    for (int r=0;r<4;r++) bufA[(hh*4+r)*256 + n] = acc[r];
  }
  __syncthreads();                                        // B12
  // P12: wave r: leaky + full softmax for edge r; write masked p
  if (wid < 4){
    int r = wid;
    float b2v = wb2[0];
    float c0 = c0p[0];
    float x[4]; bool msk[4];
    #pragma unroll
    for (int q=0;q<4;q++){
      int n = lane + 64*q;
      msk[q] = (Hm[(size_t)(e0+r)*NN + n] != 0.f);
      float raw = msk[q] ? (bufA[(0*4+r)*256+n] + bufA[(1*4+r)*256+n] + b2v) : c0;
      x[q] = raw>0.f ? raw : 0.01f*raw;
    }
    float m = fmaxf(fmaxf(x[0],x[1]), fmaxf(x[2],x[3]));
    #pragma unroll
    for (int s2=32;s2>0;s2>>=1) m = fmaxf(m, __shfl_xor(m, s2, 64));
    float p[4]; float ss=0.f;
    #pragma unroll
    for (int q=0;q<4;q++){ p[q]=expf(x[q]-m); ss+=p[q]; }
    #pragma unroll
    for (int s2=32;s2>0;s2>>=1) ss += __shfl_xor(ss, s2, 64);
    float inv = 1.f/ss;
    #pragma unroll
    for (int q=0;q<4;q++){
      int n = lane + 64*q;
      bufA[2048 + r*256 + n] = msk[q] ? p[q]*inv : 0.f;
    }
  }
  __syncthreads();                                        // B13
  // P13: assemble float4 -> HwT
  if (t < 256){
    int n = t;
    float4 o4;
    o4.x = bufA[2048 + 0*256 + n];
    o4.y = bufA[2048 + 1*256 + n];
    o4.z = bufA[2048 + 2*256 + n];
    o4.w = bufA[2048 + 3*256 + n];
    int eb = e0 & 511;
    *(float4*)(HwT + ((size_t)(b*NN)+n)*EE + eb) = o4;
  }
}

// =========================================================================
// K3 agent: msg + q2 + attention + out-proj + final MLP
// R=2 rows/block, 256 blocks, 512 threads; k2T coalesced QK
// =========================================================================
__global__ __launch_bounds__(512) void agent_kernel(
                             const float* HwT, const float* edgef, const float* ete,
                             const float* af,
                             const float* qW, const float* qb, const float* iqW, const float* iqb,
                             const float* k2T, const float* v2,
                             const float* op_W, const float* op_b,
                             const float* oW1, const float* ob1,
                             const float* oW2, const float* ob2,
                             float* pnew, float* anew){
  __shared__ int   ecomp[2][EE];      // 4KB
  __shared__ float wcomp[2][EE];      // 4KB
  __shared__ int   wcnt[2][4];
  __shared__ float agfl[2][512];      // [msg(256) | af(128) | pnew(128)]
  __shared__ float part[4096];        // 16KB
  __shared__ float Qs[2][DD];
  __shared__ float qr[2][DD];
  __shared__ float att[2][4][PP+1];   // 8.2KB
  __shared__ float o_l[2][DD];
  __shared__ float hid[2][HDIM];
  int n0 = blockIdx.x*2; int b = n0 >> 8; int t = threadIdx.x;  // 512
  int tt = t & 255, rr = t >> 8;
  int lane = t & 63, wid = t >> 6;    // global wave 0..7
  int lw = tt >> 6;                   // wave within row-half 0..3

  // ---- msg: both rows compact in parallel (row = wave-half) ----
  {
    int bn = n0 + rr;
    const float* wrow = HwT + (size_t)bn*EE;
    int total = 0;
    #pragma unroll
    for (int p=0;p<2;p++){
      int e = p*256 + tt;
      float w = wrow[e];
      bool pred = (w != 0.f);
      unsigned long long mask = __ballot(pred);
      if (lane==0) wcnt[rr][lw] = __popcll(mask);
      int off = __popcll(mask & ((1ull<<lane)-1ull));
      __syncthreads();
      int wb = total;
      for (int ww=0; ww<lw; ww++) wb += wcnt[rr][ww];
      if (pred){ ecomp[rr][wb+off] = e; wcomp[rr][wb+off] = w; }
      total += wcnt[rr][0]+wcnt[rr][1]+wcnt[rr][2]+wcnt[rr][3];
      __syncthreads();
    }
    float acc = 0.f;
    const float* srcbase = (tt < DD) ? (edgef + (size_t)b*EE*DD + tt)
                                     : (ete   + (size_t)b*EE*DD + (tt-DD));
    for (int i=0;i<total;i++){
      acc += wcomp[rr][i] * srcbase[(size_t)ecomp[rr][i]*DD];
    }
    agfl[rr][tt] = acc;
    if (tt < DD) agfl[rr][2*DD+tt] = af[(size_t)bn*DD + tt];
  }
  __syncthreads();
  int c=(tt&31)*4, ps=tt>>5;          // per-row-half decomposition
  // ---- q2 stage1: (2 x 384) @ (384 x 128) ----
  {
    float4 a = make_float4(0.f,0.f,0.f,0.f);
    #pragma unroll 4
    for (int i=ps*48;i<ps*48+48;i++){
      float4 w = *(const float4*)&qW[(size_t)i*DD+c];
      f4fma(a, agfl[rr][i], w);
    }
    *(float4*)&part[(rr*8+ps)*DD+c]=a;
  }
  __syncthreads();
  if (t<256){
    int cc=t&127, r=t>>7;
    float s=0.f;
    #pragma unroll
    for (int k=0;k<8;k++) s+=part[(r*8+k)*DD+cc];
    Qs[r][cc]=s+qb[cc];
  }
  __syncthreads();
  // ---- q2 stage2 ----
  {
    float4 a = make_float4(0.f,0.f,0.f,0.f);
    #pragma unroll 4
    for (int i=ps*16;i<ps*16+16;i++){
      float4 w = *(const float4*)&iqW[(size_t)i*DD+c];
      f4fma(a, Qs[rr][i], w);
    }
    *(float4*)&part[(rr*8+ps)*DD+c]=a;
  }
  __syncthreads();
  if (t<256){
    int cc=t&127, r=t>>7;
    float s=0.f;
    #pragma unroll
    for (int k=0;k<8;k++) s+=part[(r*8+k)*DD+cc];
    qr[r][cc]=s+iqb[cc];
  }
  __syncthreads();
  // ---- attention scores: p=tt, head-pair=rr, both rows; k2T coalesced ----
  const float scale = 0.17677669529663687f;  // 1/sqrt(32)
  {
    const float* KTb = k2T + (size_t)b*DD*PP + tt;
    #pragma unroll
    for (int hh=0;hh<2;hh++){
      int h = rr*2+hh;
      float s0=0.f, s1=0.f;
      #pragma unroll 8
      for (int j=0;j<32;j++){
        float kv = KTb[(size_t)(h*32+j)*PP];
        s0 += qr[0][h*32+j]*kv;
        s1 += qr[1][h*32+j]*kv;
      }
      att[0][h][tt] = s0*scale;
      att[1][h][tt] = s1*scale;
    }
  }
  __syncthreads();
  // ---- softmax: 8 waves = 8 (row, head) pairs ----
  {
    int r = wid>>2, h = wid&3;
    float v0 = att[r][h][lane],     v1 = att[r][h][lane+64],
          ve = att[r][h][lane+128], v3 = att[r][h][lane+192];
    float m = fmaxf(fmaxf(v0,v1), fmaxf(ve,v3));
    #pragma unroll
    for (int s2=32;s2>0;s2>>=1) m = fmaxf(m, __shfl_xor(m, s2, 64));
    float e0 = expf(v0-m), e1 = expf(v1-m), e2 = expf(ve-m), e3 = expf(v3-m);
    float ss = (e0+e1)+(e2+e3);
    #pragma unroll
    for (int s2=32;s2>0;s2>>=1) ss += __shfl_xor(ss, s2, 64);
    float inv = 1.f/ss;
    att[r][h][lane] = e0*inv; att[r][h][lane+64] = e1*inv;
    att[r][h][lane+128] = e2*inv; att[r][h][lane+192] = e3*inv;
  }
  __syncthreads();
  // ---- PV: row rr, 8-way p-split ----
  int h2 = c >> 5;
  {
    float4 acc = make_float4(0.f,0.f,0.f,0.f);
    #pragma unroll 4
    for (int i=0;i<32;i++){
      int p = ps*32+i;
      float4 v = *(const float4*)&v2[((size_t)(b*PP)+p)*DD + c];
      f4fma(acc, att[rr][h2][p], v);
    }
    *(float4*)&part[(rr*8+ps)*DD+c]=acc;
  }
  __syncthreads();
  if (t<256){
    int cc=t&127, r=t>>7;
    float s=0.f;
    #pragma unroll
    for (int k=0;k<8;k++) s+=part[(r*8+k)*DD+cc];
    o_l[r][cc]=s;
  }
  __syncthreads();
  // ---- out-proj -> pnew + LDS ----
  {
    float4 a2 = make_float4(0.f,0.f,0.f,0.f);
    #pragma unroll 4
    for (int i=ps*16;i<ps*16+16;i++){
      float4 w = *(const float4*)&op_W[(size_t)i*DD + c];
      f4fma(a2, o_l[rr][i], w);
    }
    *(float4*)&part[(rr*8+ps)*DD+c]=a2;
  }
  __syncthreads();
  if (t<256){
    int cc=t&127, r=t>>7;
    float s=0.f;
    #pragma unroll
    for (int k=0;k<8;k++) s+=part[(r*8+k)*DD+cc];
    float pv = s+op_b[cc];
    agfl[r][3*DD+cc] = pv;
    pnew[(size_t)(n0+r)*DD+cc] = pv;
  }
  __syncthreads();
  // ---- final stage1: (2 x 512) @ (512 x 256), 8-way k-split (slices 64) ----
  {
    int c1=(t&63)*4, ks1=t>>6;
    float4 acc[2];
    #pragma unroll
    for (int r=0;r<2;r++) acc[r]=make_float4(0.f,0.f,0.f,0.f);
    #pragma unroll 8
    for (int i=ks1*64;i<ks1*64+64;i++){
      float4 w = *(const float4*)&oW1[(size_t)i*HDIM+c1];
      f4fma(acc[0], agfl[0][i], w);
      f4fma(acc[1], agfl[1][i], w);
    }
    #pragma unroll
    for (int r=0;r<2;r++) *(float4*)&part[(ks1*2+r)*HDIM+c1]=acc[r];
  }
  __syncthreads();
  {
    int h=t&255, r=t>>8;
    float s=0.f;
    #pragma unroll
    for (int k=0;k<8;k++) s+=part[(k*2+r)*HDIM+h];
    hid[r][h] = fmaxf(s+ob1[h], 0.f);
  }
  __syncthreads();
  // ---- final stage2: (2 x 256) @ (256 x 128), row rr, 8-way h-split ----
  {
    float4 a2 = make_float4(0.f,0.f,0.f,0.f);
    #pragma unroll 8
    for (int h=ps*32;h<ps*32+32;h++){
      float4 w = *(const float4*)&oW2[(size_t)h*DD+c];
      f4fma(a2, hid[rr][h], w);
    }
    *(float4*)&part[(rr*8+ps)*DD+c]=a2;
  }
  __syncthreads();
  if (t<256){
    int cc=t&127, r=t>>7;
    float s=0.f;
    #pragma unroll
    for (int k=0;k<8;k++) s+=part[(r*8+k)*DD+cc];
    anew[(size_t)(n0+r)*DD+cc]=s+ob2[cc];
  }
}

extern "C" void kernel_launch(void* const* d_in, const int* in_sizes, int n_in,
                              void* d_out, int out_size, void* d_ws, size_t ws_size,
                              hipStream_t stream) {
  const float* af       = (const float*)d_in[0];
  const float* at       = (const float*)d_in[1];
  const float* pf       = (const float*)d_in[2];
  const float* Hm       = (const float*)d_in[3];
  const float* type_emb = (const float*)d_in[4];
  const float* w_W1 = (const float*)d_in[5];
  const float* w_b1 = (const float*)d_in[6];
  const float* w_W2 = (const float*)d_in[7];
  const float* w_b2 = (const float*)d_in[8];
  const float* d_W1 = (const float*)d_in[9];
  const float* d_b1 = (const float*)d_in[10];
  const float* d_W2 = (const float*)d_in[11];
  const float* d_b2 = (const float*)d_in[12];
  const float* f_W1 = (const float*)d_in[13];
  const float* f_b1 = (const float*)d_in[14];
  const float* f_W2 = (const float*)d_in[15];
  const float* f_b2 = (const float*)d_in[16];
  const float* o_W1 = (const float*)d_in[17];
  const float* o_b1 = (const float*)d_in[18];
  const float* o_W2 = (const float*)d_in[19];
  const float* o_b2 = (const float*)d_in[20];
  const float* q_W  = (const float*)d_in[21];
  const float* q_b  = (const float*)d_in[22];
  const float* k_W  = (const float*)d_in[23];
  const float* k_b  = (const float*)d_in[24];
  const float* v_W  = (const float*)d_in[25];
  const float* v_b  = (const float*)d_in[26];
  const float* iq_W = (const float*)d_in[27];
  const float* iq_b = (const float*)d_in[28];
  const float* ik_W = (const float*)d_in[29];
  const float* ik_b = (const float*)d_in[30];
  const float* iv_W = (const float*)d_in[31];
  const float* iv_b = (const float*)d_in[32];
  const float* op_W = (const float*)d_in[33];
  const float* op_b = (const float*)d_in[34];

  float* ws   = (float*)d_ws;
  float* out  = (float*)d_out;
  float* anew = out;                 // (B,N,D)
  float* pnew = out + BB*NN*DD;      // (B,N,D)

  prep_kernel<<<PB_END, 256, 0, stream>>>(
      ws+WS_G, ws+WS_C0, w_b1, w_W2, w_b2,
      Hm, af, at, w_W1, w_b1,
      ws+WS_U1, ws+WS_ETYPE, ws+WS_VT,
      pf, k_W,k_b,ik_W,ik_b, v_W,v_b,iv_W,iv_b,
      ws+WS_K2T, ws+WS_V2);
  edge_kernel<<<256,512,0,stream>>>(
      Hm, af, ws+WS_VT, ws+WS_U1, ws+WS_ETYPE,
      w_W1, w_b1, w_W2, w_b2,
      d_W1,d_b1,d_W2,d_b2, f_W1,f_b1,f_W2,f_b2,
      type_emb, ws+WS_G, ws+WS_C0,
      ws+WS_EDGEF, ws+WS_ETE, ws+WS_HWT);
  agent_kernel<<<256,512,0,stream>>>(
      ws+WS_HWT, ws+WS_EDGEF, ws+WS_ETE, af,
      q_W, q_b, iq_W, iq_b,
      ws+WS_K2T, ws+WS_V2, op_W, op_b,
      o_W1,o_b1,o_W2,o_b2, pnew, anew);
}

// Round 14
// 87.037 us; speedup vs baseline: 2.1102x; 1.2412x over previous
//
#include <hip/hip_runtime.h>
#include <math.h>

#define BB 2
#define NN 256
#define EE 512
#define PP 256
#define DD 128
#define TT 8
#define KK 8
#define HDIM 256

// workspace offsets (floats)
#define WS_G      0          // 8192
#define WS_C0     8192       // 64
#define WS_V      8256       // B*N*HD = 131072
#define WS_U1     139328     // B*E*HD = 262144
#define WS_ETYPE  401472     // B*E*T = 8192
#define WS_EDGEF  409664     // B*E*D = 131072
#define WS_ETE    540736     // B*E*D = 131072
#define WS_HWT    671808     // B*N*E = 262144
#define WS_K2     933952     // 65536
#define WS_V2     999488     // 65536
// total 1065024 floats = 4.26 MB

// prep grid roles
#define PB_GUM 16
#define PB_INC 272    // +256 incidence+U1 blocks (R=4 edges)
#define PB_V   528    // +256 V-MLP blocks (R=2)
#define PB_END 784    // +256 kv blocks (R=2)

__device__ inline unsigned rotl32(unsigned x, int d){ return (x<<d)|(x>>(32-d)); }

__device__ inline float bits_to_gumbel(unsigned bits){
  float f = __uint_as_float((bits>>9)|0x3f800000u) - 1.0f;
  const float minv = 1e-6f;
  const float maxv = 1.0f - 1e-6f;
  float u = f*(maxv-minv) + minv;
  u = fmaxf(minv, u);
  return -logf(-logf(u));
}

__device__ __forceinline__ void f4fma(float4& a, float x, const float4& w){
  a.x += x*w.x; a.y += x*w.y; a.z += x*w.z; a.w += x*w.w;
}

__device__ __forceinline__ void block_reduce2_sum(float v[2], float* wred){
  int lane = threadIdx.x & 63, wid = threadIdx.x >> 6;
  #pragma unroll
  for (int s=32;s>0;s>>=1){
    #pragma unroll
    for (int r=0;r<2;r++){ v[r] += __shfl_xor(v[r], s, 64); }
  }
  if (lane==0){
    #pragma unroll
    for (int r=0;r<2;r++) wred[wid*2+r]=v[r];
  }
  __syncthreads();
  #pragma unroll
  for (int r=0;r<2;r++)
    v[r] = (wred[0*2+r]+wred[1*2+r]) + (wred[2*2+r]+wred[3*2+r]);
  __syncthreads();
}

// ---- 2 rows x (128->128) dense layer, float4 + 8-way k-split (256 t) ----
__device__ __forceinline__ void mlp128_lds2(const float (*in)[DD], const float* W, const float* bias,
                                            float (*outl)[DD], float* part, int t){
  int c=(t&31)*4, ks=t>>5;
  float4 a[2];
  #pragma unroll
  for (int r=0;r<2;r++) a[r]=make_float4(0.f,0.f,0.f,0.f);
  #pragma unroll 4
  for (int i=ks*16;i<ks*16+16;i++){
    float4 w = *(const float4*)&W[(size_t)i*DD+c];
    #pragma unroll
    for (int r=0;r<2;r++) f4fma(a[r], in[r][i], w);
  }
  #pragma unroll
  for (int r=0;r<2;r++) *(float4*)&part[(ks*2+r)*DD+c]=a[r];
  __syncthreads();
  int cc=t&127, r=t>>7;
  {
    float s=0.f;
    #pragma unroll
    for (int k2=0;k2<8;k2++) s+=part[(k2*2+r)*DD+cc];
    outl[r][cc]=s+bias[cc];
  }
  __syncthreads();
}

__device__ __forceinline__ void mlp128_glob2(const float (*in)[DD], const float* W, const float* bias,
                                             float* dst, int r0, float* part, int t){
  int c=(t&31)*4, ks=t>>5;
  float4 a[2];
  #pragma unroll
  for (int r=0;r<2;r++) a[r]=make_float4(0.f,0.f,0.f,0.f);
  #pragma unroll 4
  for (int i=ks*16;i<ks*16+16;i++){
    float4 w = *(const float4*)&W[(size_t)i*DD+c];
    #pragma unroll
    for (int r=0;r<2;r++) f4fma(a[r], in[r][i], w);
  }
  #pragma unroll
  for (int r=0;r<2;r++) *(float4*)&part[(ks*2+r)*DD+c]=a[r];
  __syncthreads();
  int cc=t&127, r=t>>7;
  {
    float s=0.f;
    #pragma unroll
    for (int k2=0;k2<8;k2++) s+=part[(k2*2+r)*DD+cc];
    dst[(size_t)(r0+r)*DD+cc]=s+bias[cc];
  }
  __syncthreads();
}

// =========================================================================
// K1 prep: gumbel+c0 | incidence+U1 (R=4) | V-MLP (R=2) | k2/v2 (R=2)
// =========================================================================
__global__ void prep_kernel(float* g, float* c0, const float* w_b1,
                            const float* w_W2, const float* w_b2,
                            const float* Hm, const float* af, const float* at,
                            const float* wW1, const float* wb1,
                            float* U1g, float* etype_g, float* Vout,
                            const float* pf,
                            const float* kW, const float* kb, const float* ikW, const float* ikb,
                            const float* vW, const float* vb, const float* ivW, const float* ivb,
                            float* k2, float* v2){
  __shared__ float part[4096];       // 16KB
  __shared__ float wred[16];
  __shared__ int   hcomp[4*256];     // 4KB
  __shared__ int   hcnt[4];
  __shared__ float ef[4][DD];        // 2KB
  __shared__ float xs[2][DD];
  __shared__ float bufB[2][DD];
  int blk = blockIdx.x;
  int t = threadIdx.x;               // 256
  int lane = t & 63, wid = t >> 6;

  if (blk < PB_GUM){
    int j = blk*256 + t;
    {
      const unsigned k0=0u, k1=42u;
      const unsigned ks2 = k0^k1^0x1BD11BDAu;
      unsigned x0 = (unsigned)j, x1 = (unsigned)j + 4096u;
      const int r0_[4]={13,15,26,6}, r1_[4]={17,29,16,24};
      x0 += k0; x1 += k1;
      #pragma unroll
      for(int i=0;i<4;i++){ x0+=x1; x1=rotl32(x1,r0_[i]); x1^=x0; }
      x0+=k1; x1+=ks2+1u;
      #pragma unroll
      for(int i=0;i<4;i++){ x0+=x1; x1=rotl32(x1,r1_[i]); x1^=x0; }
      x0+=ks2; x1+=k0+2u;
      #pragma unroll
      for(int i=0;i<4;i++){ x0+=x1; x1=rotl32(x1,r0_[i]); x1^=x0; }
      x0+=k0; x1+=k1+3u;
      #pragma unroll
      for(int i=0;i<4;i++){ x0+=x1; x1=rotl32(x1,r1_[i]); x1^=x0; }
      x0+=k1; x1+=ks2+4u;
      #pragma unroll
      for(int i=0;i<4;i++){ x0+=x1; x1=rotl32(x1,r0_[i]); x1^=x0; }
      x0+=ks2; x1+=k0+5u;
      g[j]      = bits_to_gumbel(x0);
      g[j+4096] = bits_to_gumbel(x1);
    }
    if (blk == 0){
      float v4[2];
      v4[0] = fmaxf(w_b1[t],0.f)*w_W2[t]; v4[1]=0.f;
      block_reduce2_sum(v4, wred);
      if (t==0) c0[0] = v4[0] + w_b2[0];
    }
  } else if (blk < PB_INC){
    // ---- incidence + U1, R=4 edges ----
    int e0 = (blk - PB_GUM)*4;
    int b = e0 >> 9;
    {
      int r = wid;
      const float* Hrow = Hm + (size_t)(e0+r)*NN;
      int base = 0;
      #pragma unroll
      for (int c4=0;c4<4;c4++){
        int n2 = c4*64 + lane;
        bool pred = (Hrow[n2] != 0.f);
        unsigned long long mask = __ballot(pred);
        int off = __popcll(mask & ((1ull<<lane)-1ull));
        if (pred) hcomp[r*256+base+off] = n2;
        base += __popcll(mask);
      }
      if (lane==0) hcnt[r] = base;
    }
    __syncthreads();
    {
      int d = t & 127, eh = t >> 7;
      #pragma unroll
      for (int rr=0;rr<2;rr++){
        int r = eh*2 + rr;
        int tot = hcnt[r];
        float a = 0.f, a2 = 0.f;
        for (int i=0;i<tot;i++){
          int n2 = hcomp[r*256+i];
          a += af[((size_t)b*NN+n2)*DD + d];
          if (d < TT) a2 += at[((size_t)b*NN+n2)*TT + d];
        }
        ef[r][d] = a;
        if (d < TT) etype_g[(size_t)(e0+r)*TT + d] = a2;
      }
    }
    __syncthreads();
    {
      int c = (t&63)*4, ks = t>>6;
      float4 acc[4];
      #pragma unroll
      for (int r=0;r<4;r++) acc[r]=make_float4(0.f,0.f,0.f,0.f);
      #pragma unroll 8
      for (int i=ks*32; i<ks*32+32; i++){
        float4 w = *(const float4*)&wW1[(size_t)i*HDIM + c];
        #pragma unroll
        for (int r=0;r<4;r++) f4fma(acc[r], ef[r][i], w);
      }
      #pragma unroll
      for (int r=0;r<4;r++) *(float4*)&part[(ks*4+r)*HDIM + c] = acc[r];
    }
    __syncthreads();
    {
      float bv = wb1[t];
      #pragma unroll
      for (int r=0;r<4;r++){
        float s = (part[(0*4+r)*HDIM+t] + part[(1*4+r)*HDIM+t])
                + (part[(2*4+r)*HDIM+t] + part[(3*4+r)*HDIM+t]);
        U1g[(size_t)(e0+r)*HDIM + t] = s + bv;
      }
    }
  } else if (blk < PB_V){
    int r0 = (blk - PB_INC)*2;
    const float* W = wW1 + (size_t)DD*HDIM;
    for (int i=t;i<2*DD;i+=256) xs[i>>7][i&127] = af[(size_t)(r0+(i>>7))*DD + (i&127)];
    __syncthreads();
    int c = (t&63)*4, ks = t>>6;
    float4 acc[2];
    #pragma unroll
    for (int r=0;r<2;r++) acc[r]=make_float4(0.f,0.f,0.f,0.f);
    #pragma unroll 8
    for (int i=ks*32; i<ks*32+32; i++){
      float4 w = *(const float4*)&W[(size_t)i*HDIM + c];
      #pragma unroll
      for (int r=0;r<2;r++) f4fma(acc[r], xs[r][i], w);
    }
    #pragma unroll
    for (int r=0;r<2;r++) *(float4*)&part[(ks*2+r)*HDIM + c] = acc[r];
    __syncthreads();
    #pragma unroll
    for (int r=0;r<2;r++){
      float s = (part[(0*2+r)*HDIM+t] + part[(1*2+r)*HDIM+t])
              + (part[(2*2+r)*HDIM+t] + part[(3*2+r)*HDIM+t]);
      Vout[(size_t)(r0+r)*HDIM + t] = s;
    }
  } else {
    int r0 = (blk - PB_V)*2;
    for (int i=t;i<2*DD;i+=256) xs[i>>7][i&127] = pf[(size_t)(r0+(i>>7))*DD + (i&127)];
    __syncthreads();
    mlp128_lds2 (xs, kW, kb, bufB, part, t);
    mlp128_glob2(bufB, ikW, ikb, k2, r0, part, t);
    mlp128_lds2 (xs, vW, vb, bufB, part, t);
    mlp128_glob2(bufB, ivW, ivb, v2, r0, part, t);
  }
}

// =========================================================================
// K2 edge: R=4, 256 blocks, 512 threads; fW1 preloaded in registers,
// dW1 streamed 8-way; wW1 slice in registers for U2.
// =========================================================================
__global__ __launch_bounds__(512) void edge_kernel(
                            const float* Hm, const float* af,
                            const float* Vm, const float* U1g, const float* etype_g,
                            const float* wW1, const float* wb1, const float* wW2, const float* wb2,
                            const float* dW1, const float* db1, const float* dW2, const float* db2,
                            const float* fW1, const float* fb1, const float* fW2, const float* fb2,
                            const float* type_emb, const float* g, const float* c0p,
                            float* edgef_g, float* ete_g, float* HwT){
  __shared__ float bufA[8192];        // 32KB multiplexed
  __shared__ float w2s[HDIM*KK];      // 8KB dW2
  __shared__ float w2l[HDIM];         // wW2
  __shared__ float et4[4][144];       // etype -> edgef -> ete
  __shared__ float hd4[4][HDIM];      // U1 -> relu-hidden -> U2
  __shared__ float redsm[512];
  __shared__ float wred[16];
  __shared__ float fdv[4][KK];
  __shared__ int   hcnt[4];
  __shared__ int   hcomp[4*256];      // 4KB

  int e0 = blockIdx.x*4;
  int b  = e0 >> 9;
  int t  = threadIdx.x;               // 512
  int lane = t & 63, wid = t >> 6;    // wid 0..7

  // register preloads (latency hidden behind P1-P3)
  int cW=(t&63)*4, ksW=t>>6;
  float4 wreg[16];
  #pragma unroll
  for (int i=0;i<16;i++)
    wreg[i] = *(const float4*)&wW1[(size_t)(ksW*16+i)*HDIM + cW];
  float4 freg[17];                    // fW1 rows ksW*17..+16, col cW (exactly one copy)
  #pragma unroll
  for (int i=0;i<17;i++)
    freg[i] = *(const float4*)&fW1[(size_t)(ksW*17+i)*HDIM + cW];

  if (t < HDIM) w2l[t] = wW2[t];
  for (int i=t;i<HDIM*KK;i+=512) w2s[i] = dW2[i];
  {
    int h=t&255, rh=t>>8;
    #pragma unroll
    for (int rr=0;rr<2;rr++){
      int r = 2*rh+rr;
      hd4[r][h] = U1g[(size_t)(e0+r)*HDIM + h];
    }
  }
  if (t < 32){ int r=t>>3, j=t&7; et4[r][DD+j] = etype_g[(size_t)(e0+r)*TT + j]; }
  if (wid < 4){
    int r = wid;
    const float* Hrow = Hm + (size_t)(e0+r)*NN;
    int base = 0;
    #pragma unroll
    for (int c4=0;c4<4;c4++){
      int n2 = c4*64 + lane;
      bool pred = (Hrow[n2] != 0.f);
      unsigned long long mask = __ballot(pred);
      int off = __popcll(mask & ((1ull<<lane)-1ull));
      if (pred) hcomp[r*256+base+off] = n2;
      base += __popcll(mask);
    }
    if (lane==0) hcnt[r] = base;
  }
  __syncthreads();                                        // B1
  // P1: relu-dot L1 partials (h-half split)
  {
    int n = t&255, hh = t>>8;
    const float4* Vrow = (const float4*)(Vm + ((size_t)(b*NN)+n)*HDIM);
    float acc[4]={0.f,0.f,0.f,0.f};
    #pragma unroll 4
    for (int ii=hh*32; ii<hh*32+32; ii++){
      float4 v = Vrow[ii];
      float w0=w2l[4*ii+0], w1=w2l[4*ii+1], wc=w2l[4*ii+2], w3=w2l[4*ii+3];
      #pragma unroll
      for (int r=0;r<4;r++){
        acc[r] += fmaxf(hd4[r][4*ii+0]+v.x,0.f)*w0
                + fmaxf(hd4[r][4*ii+1]+v.y,0.f)*w1
                + fmaxf(hd4[r][4*ii+2]+v.z,0.f)*wc
                + fmaxf(hd4[r][4*ii+3]+v.w,0.f)*w3;
      }
    }
    #pragma unroll
    for (int r=0;r<4;r++) bufA[(hh*4+r)*256 + n] = acc[r];
  }
  __syncthreads();                                        // B2
  // P2: wave r: full masked softmax for edge r
  if (wid < 4){
    int r = wid;
    float b2v = wb2[0];
    float x[4]; bool msk[4];
    #pragma unroll
    for (int q=0;q<4;q++){
      int n = lane + 64*q;
      msk[q] = (Hm[(size_t)(e0+r)*NN + n] != 0.f);
      x[q] = msk[q] ? (bufA[(0*4+r)*256+n] + bufA[(1*4+r)*256+n] + b2v) : 0.f;
    }
    float m = fmaxf(fmaxf(x[0],x[1]), fmaxf(x[2],x[3]));
    #pragma unroll
    for (int s2=32;s2>0;s2>>=1) m = fmaxf(m, __shfl_xor(m, s2, 64));
    float p[4]; float ss=0.f;
    #pragma unroll
    for (int q=0;q<4;q++){ p[q]=expf(x[q]-m); ss+=p[q]; }
    #pragma unroll
    for (int s2=32;s2>0;s2>>=1) ss += __shfl_xor(ss, s2, 64);
    float inv = 1.f/ss;
    #pragma unroll
    for (int q=0;q<4;q++){
      int n = lane + 64*q;
      bufA[3072 + r*256 + n] = msk[q] ? p[q]*inv : 0.f;
    }
  }
  __syncthreads();                                        // B3
  // P3: aggregate -> et4 + edgef_g
  {
    int d = t & 127, r = t >> 7;
    int tot = hcnt[r];
    float a = 0.f;
    for (int i=0;i<tot;i++){
      int n2 = hcomp[r*256+i];
      a += bufA[3072 + r*256 + n2] * af[((size_t)b*NN+n2)*DD + d];
    }
    et4[r][d] = a;
    edgef_g[(size_t)(e0+r)*DD + d] = a;
  }
  __syncthreads();                                        // B4
  // P4: d/f MLP: dW1 streamed 8-way across all threads; f from registers
  float4 accF[4];
  {
    float4 accD[4];
    #pragma unroll
    for (int r=0;r<4;r++){ accD[r]=make_float4(0.f,0.f,0.f,0.f); accF[r]=accD[r]; }
    #pragma unroll
    for (int i=0;i<17;i++){
      int idx = ksW*17 + i;
      float4 wd = *(const float4*)&dW1[(size_t)idx*HDIM + cW];
      #pragma unroll
      for (int r=0;r<4;r++){
        float x = et4[r][idx];
        f4fma(accD[r], x, wd);
        f4fma(accF[r], x, freg[i]);
      }
    }
    #pragma unroll
    for (int r=0;r<4;r++) *(float4*)&bufA[(ksW*4+r)*HDIM + cW] = accD[r];
  }
  __syncthreads();                                        // B5
  // P5a: combine d-sums -> hd4 (relu hidden)
  {
    int h=t&255, rh=t>>8;
    float bd = db1[h];
    #pragma unroll
    for (int rr=0;rr<2;rr++){
      int r = 2*rh+rr;
      float sd=0.f;
      #pragma unroll
      for (int k=0;k<8;k++) sd += bufA[(k*4+r)*HDIM+h];
      hd4[r][h] = fmaxf(sd+bd, 0.f);
    }
  }
  __syncthreads();                                        // B5b
  // P5b: write f-partials
  {
    #pragma unroll
    for (int r=0;r<4;r++) *(float4*)&bufA[(ksW*4+r)*HDIM + cW] = accF[r];
  }
  __syncthreads();                                        // B5c
  // P5c: combine f-sums -> wave partials -> wred
  {
    int h=t&255, rh=t>>8;
    float bf = fb1[h], fw = fW2[h];
    float val[2];
    #pragma unroll
    for (int rr=0;rr<2;rr++){
      int r = 2*rh+rr;
      float sf=0.f;
      #pragma unroll
      for (int k=0;k<8;k++) sf += bufA[(k*4+r)*HDIM+h];
      val[rr] = fmaxf(sf+bf,0.f)*fw;
    }
    #pragma unroll
    for (int s2=32;s2>0;s2>>=1){
      val[0] += __shfl_xor(val[0], s2, 64);
      val[1] += __shfl_xor(val[1], s2, 64);
    }
    if (lane==0){ wred[wid*2]=val[0]; wred[wid*2+1]=val[1]; }
  }
  __syncthreads();                                        // B6
  // P6: logits partials
  {
    int r_ = t>>7, rem = t&127, k_ = rem&7, j_ = rem>>3;
    float lp = 0.f;
    #pragma unroll 4
    for (int i=0;i<16;i++){
      int h = j_ + 16*i;
      lp += hd4[r_][h]*w2s[h*KK + k_];
    }
    redsm[t] = lp;
  }
  __syncthreads();                                        // B7
  // P7: wave 0 (32 lanes): facs + logits-combine + gumbel softmax -> fdv
  if (wid == 0 && lane < 32){
    int r = lane>>3, k = lane&7;
    int base = (r>=2)?4:0, off = r&1;
    float fs = 0.f;
    #pragma unroll
    for (int w=0;w<4;w++) fs += wred[(base+w)*2 + off];
    float fac = 1.f/(1.f+expf(-(fs+fb2[0])));
    float s = db2[k] + g[(size_t)(e0+r)*KK + k];
    #pragma unroll
    for (int j=0;j<16;j++) s += redsm[r*128 + j*8 + k];
    float z = s*2.0f;                 // /tau
    float m = z;
    m = fmaxf(m, __shfl_xor(m, 1, 64));
    m = fmaxf(m, __shfl_xor(m, 2, 64));
    m = fmaxf(m, __shfl_xor(m, 4, 64));
    float pz = expf(z - m);
    float sum = pz;
    sum += __shfl_xor(sum, 1, 64);
    sum += __shfl_xor(sum, 2, 64);
    sum += __shfl_xor(sum, 4, 64);
    fdv[r][k] = fac * pz / sum;
  }
  __syncthreads();                                        // B8
  // P8: ete
  {
    int d = t&127, r = t>>7;
    float a = 0.f;
    #pragma unroll
    for (int k=0;k<KK;k++) a += fdv[r][k]*type_emb[(size_t)k*DD + d];
    et4[r][d] = a;
    ete_g[(size_t)(e0+r)*DD + d] = a;
  }
  __syncthreads();                                        // B9
  // P9: U2 partials from registers
  {
    float4 acc[4];
    #pragma unroll
    for (int r=0;r<4;r++) acc[r]=make_float4(0.f,0.f,0.f,0.f);
    #pragma unroll
    for (int i=0;i<16;i++){
      int idx = ksW*16 + i;
      #pragma unroll
      for (int r=0;r<4;r++) f4fma(acc[r], et4[r][idx], wreg[i]);
    }
    #pragma unroll
    for (int r=0;r<4;r++) *(float4*)&bufA[(ksW*4+r)*HDIM + cW] = acc[r];
  }
  __syncthreads();                                        // B10
  // P10: U2 sums -> hd4
  {
    int h=t&255, rh=t>>8;
    float bv = wb1[h];
    #pragma unroll
    for (int rr=0;rr<2;rr++){
      int r = 2*rh+rr;
      float s=0.f;
      #pragma unroll
      for (int k=0;k<8;k++) s += bufA[(k*4+r)*HDIM + h];
      hd4[r][h] = s + bv;
    }
  }
  __syncthreads();                                        // B11
  // P11: hw2 relu-dot partials
  {
    int n = t&255, hh = t>>8;
    const float4* Vrow = (const float4*)(Vm + ((size_t)(b*NN)+n)*HDIM);
    float acc[4]={0.f,0.f,0.f,0.f};
    #pragma unroll 4
    for (int ii=hh*32; ii<hh*32+32; ii++){
      float4 v = Vrow[ii];
      float w0=w2l[4*ii+0], w1=w2l[4*ii+1], wc=w2l[4*ii+2], w3=w2l[4*ii+3];
      #pragma unroll
      for (int r=0;r<4;r++){
        acc[r] += fmaxf(hd4[r][4*ii+0]+v.x,0.f)*w0
                + fmaxf(hd4[r][4*ii+1]+v.y,0.f)*w1
                + fmaxf(hd4[r][4*ii+2]+v.z,0.f)*wc
                + fmaxf(hd4[r][4*ii+3]+v.w,0.f)*w3;
      }
    }
    #pragma unroll
    for (int r=0;r<4;r++) bufA[(hh*4+r)*256 + n] = acc[r];
  }
  __syncthreads();                                        // B12
  // P12: wave r: leaky + full softmax; write masked p
  if (wid < 4){
    int r = wid;
    float b2v = wb2[0];
    float c0 = c0p[0];
    float x[4]; bool msk[4];
    #pragma unroll
    for (int q=0;q<4;q++){
      int n = lane + 64*q;
      msk[q] = (Hm[(size_t)(e0+r)*NN + n] != 0.f);
      float raw = msk[q] ? (bufA[(0*4+r)*256+n] + bufA[(1*4+r)*256+n] + b2v) : c0;
      x[q] = raw>0.f ? raw : 0.01f*raw;
    }
    float m = fmaxf(fmaxf(x[0],x[1]), fmaxf(x[2],x[3]));
    #pragma unroll
    for (int s2=32;s2>0;s2>>=1) m = fmaxf(m, __shfl_xor(m, s2, 64));
    float p[4]; float ss=0.f;
    #pragma unroll
    for (int q=0;q<4;q++){ p[q]=expf(x[q]-m); ss+=p[q]; }
    #pragma unroll
    for (int s2=32;s2>0;s2>>=1) ss += __shfl_xor(ss, s2, 64);
    float inv = 1.f/ss;
    #pragma unroll
    for (int q=0;q<4;q++){
      int n = lane + 64*q;
      bufA[2048 + r*256 + n] = msk[q] ? p[q]*inv : 0.f;
    }
  }
  __syncthreads();                                        // B13
  // P13: assemble float4 -> HwT
  if (t < 256){
    int n = t;
    float4 o4;
    o4.x = bufA[2048 + 0*256 + n];
    o4.y = bufA[2048 + 1*256 + n];
    o4.z = bufA[2048 + 2*256 + n];
    o4.w = bufA[2048 + 3*256 + n];
    int eb = e0 & 511;
    *(float4*)(HwT + ((size_t)(b*NN)+n)*EE + eb) = o4;
  }
}

// =========================================================================
// K3 agent: msg + q2 + attention + out-proj + final MLP
// R=2 rows/block, 256 blocks, 512 threads
// =========================================================================
__global__ __launch_bounds__(512) void agent_kernel(
                             const float* HwT, const float* edgef, const float* ete,
                             const float* af,
                             const float* qW, const float* qb, const float* iqW, const float* iqb,
                             const float* k2, const float* v2,
                             const float* op_W, const float* op_b,
                             const float* oW1, const float* ob1,
                             const float* oW2, const float* ob2,
                             float* pnew, float* anew){
  __shared__ int   ecomp[2][EE];      // 4KB
  __shared__ float wcomp[2][EE];      // 4KB
  __shared__ int   wcnt[2][4];
  __shared__ float agfl[2][512];      // [msg(256) | af(128) | pnew(128)]
  __shared__ float part[4096];        // 16KB
  __shared__ float Qs[2][DD];
  __shared__ float qr[2][DD];
  __shared__ float att[2][4][PP+1];   // 8.2KB
  __shared__ float o_l[2][DD];
  __shared__ float hid[2][HDIM];
  int n0 = blockIdx.x*2; int b = n0 >> 8; int t = threadIdx.x;  // 512
  int tt = t & 255, rr = t >> 8;
  int lane = t & 63, wid = t >> 6;    // global wave 0..7
  int lw = tt >> 6;                   // wave within row-half 0..3

  // ---- msg: both rows compact in parallel (row = wave-half) ----
  {
    int bn = n0 + rr;
    const float* wrow = HwT + (size_t)bn*EE;
    int total = 0;
    #pragma unroll
    for (int p=0;p<2;p++){
      int e = p*256 + tt;
      float w = wrow[e];
      bool pred = (w != 0.f);
      unsigned long long mask = __ballot(pred);
      if (lane==0) wcnt[rr][lw] = __popcll(mask);
      int off = __popcll(mask & ((1ull<<lane)-1ull));
      __syncthreads();
      int wb = total;
      for (int ww=0; ww<lw; ww++) wb += wcnt[rr][ww];
      if (pred){ ecomp[rr][wb+off] = e; wcomp[rr][wb+off] = w; }
      total += wcnt[rr][0]+wcnt[rr][1]+wcnt[rr][2]+wcnt[rr][3];
      __syncthreads();
    }
    float acc = 0.f;
    const float* srcbase = (tt < DD) ? (edgef + (size_t)b*EE*DD + tt)
                                     : (ete   + (size_t)b*EE*DD + (tt-DD));
    for (int i=0;i<total;i++){
      acc += wcomp[rr][i] * srcbase[(size_t)ecomp[rr][i]*DD];
    }
    agfl[rr][tt] = acc;
    if (tt < DD) agfl[rr][2*DD+tt] = af[(size_t)bn*DD + tt];
  }
  __syncthreads();
  int c=(tt&31)*4, ps=tt>>5;          // per-row-half decomposition
  // ---- q2 stage1: (2 x 384) @ (384 x 128) ----
  {
    float4 a = make_float4(0.f,0.f,0.f,0.f);
    #pragma unroll 4
    for (int i=ps*48;i<ps*48+48;i++){
      float4 w = *(const float4*)&qW[(size_t)i*DD+c];
      f4fma(a, agfl[rr][i], w);
    }
    *(float4*)&part[(rr*8+ps)*DD+c]=a;
  }
  __syncthreads();
  if (t<256){
    int cc=t&127, r=t>>7;
    float s=0.f;
    #pragma unroll
    for (int k=0;k<8;k++) s+=part[(r*8+k)*DD+cc];
    Qs[r][cc]=s+qb[cc];
  }
  __syncthreads();
  // ---- q2 stage2 ----
  {
    float4 a = make_float4(0.f,0.f,0.f,0.f);
    #pragma unroll 4
    for (int i=ps*16;i<ps*16+16;i++){
      float4 w = *(const float4*)&iqW[(size_t)i*DD+c];
      f4fma(a, Qs[rr][i], w);
    }
    *(float4*)&part[(rr*8+ps)*DD+c]=a;
  }
  __syncthreads();
  if (t<256){
    int cc=t&127, r=t>>7;
    float s=0.f;
    #pragma unroll
    for (int k=0;k<8;k++) s+=part[(r*8+k)*DD+cc];
    qr[r][cc]=s+iqb[cc];
  }
  __syncthreads();
  // ---- attention scores: p=tt, head-pair=rr, both rows ----
  const float scale = 0.17677669529663687f;  // 1/sqrt(32)
  {
    const float* krow = k2 + ((size_t)(b*PP) + tt)*DD;
    #pragma unroll
    for (int hh=0;hh<2;hh++){
      int h = rr*2+hh;
      const float4* k4 = (const float4*)(krow + h*32);
      float s0=0.f, s1=0.f;
      #pragma unroll
      for (int jj=0;jj<8;jj++){
        float4 kk = k4[jj];
        s0 += qr[0][h*32+jj*4+0]*kk.x + qr[0][h*32+jj*4+1]*kk.y
            + qr[0][h*32+jj*4+2]*kk.z + qr[0][h*32+jj*4+3]*kk.w;
        s1 += qr[1][h*32+jj*4+0]*kk.x + qr[1][h*32+jj*4+1]*kk.y
            + qr[1][h*32+jj*4+2]*kk.z + qr[1][h*32+jj*4+3]*kk.w;
      }
      att[0][h][tt] = s0*scale;
      att[1][h][tt] = s1*scale;
    }
  }
  __syncthreads();
  // ---- softmax: 8 waves = 8 (row, head) pairs ----
  {
    int r = wid>>2, h = wid&3;
    float v0 = att[r][h][lane],     v1 = att[r][h][lane+64],
          ve = att[r][h][lane+128], v3 = att[r][h][lane+192];
    float m = fmaxf(fmaxf(v0,v1), fmaxf(ve,v3));
    #pragma unroll
    for (int s2=32;s2>0;s2>>=1) m = fmaxf(m, __shfl_xor(m, s2, 64));
    float e0 = expf(v0-m), e1 = expf(v1-m), e2 = expf(ve-m), e3 = expf(v3-m);
    float ss = (e0+e1)+(e2+e3);
    #pragma unroll
    for (int s2=32;s2>0;s2>>=1) ss += __shfl_xor(ss, s2, 64);
    float inv = 1.f/ss;
    att[r][h][lane] = e0*inv; att[r][h][lane+64] = e1*inv;
    att[r][h][lane+128] = e2*inv; att[r][h][lane+192] = e3*inv;
  }
  __syncthreads();
  // ---- PV: row rr, 8-way p-split ----
  int h2 = c >> 5;
  {
    float4 acc = make_float4(0.f,0.f,0.f,0.f);
    #pragma unroll 4
    for (int i=0;i<32;i++){
      int p = ps*32+i;
      float4 v = *(const float4*)&v2[((size_t)(b*PP)+p)*DD + c];
      f4fma(acc, att[rr][h2][p], v);
    }
    *(float4*)&part[(rr*8+ps)*DD+c]=acc;
  }
  __syncthreads();
  if (t<256){
    int cc=t&127, r=t>>7;
    float s=0.f;
    #pragma unroll
    for (int k=0;k<8;k++) s+=part[(r*8+k)*DD+cc];
    o_l[r][cc]=s;
  }
  __syncthreads();
  // ---- out-proj -> pnew + LDS ----
  {
    float4 a2 = make_float4(0.f,0.f,0.f,0.f);
    #pragma unroll 4
    for (int i=ps*16;i<ps*16+16;i++){
      float4 w = *(const float4*)&op_W[(size_t)i*DD + c];
      f4fma(a2, o_l[rr][i], w);
    }
    *(float4*)&part[(rr*8+ps)*DD+c]=a2;
  }
  __syncthreads();
  if (t<256){
    int cc=t&127, r=t>>7;
    float s=0.f;
    #pragma unroll
    for (int k=0;k<8;k++) s+=part[(r*8+k)*DD+cc];
    float pv = s+op_b[cc];
    agfl[r][3*DD+cc] = pv;
    pnew[(size_t)(n0+r)*DD+cc] = pv;
  }
  __syncthreads();
  // ---- final stage1: (2 x 512) @ (512 x 256), 8-way k-split (slices 64) ----
  {
    int c1=(t&63)*4, ks1=t>>6;
    float4 acc[2];
    #pragma unroll
    for (int r=0;r<2;r++) acc[r]=make_float4(0.f,0.f,0.f,0.f);
    #pragma unroll 8
    for (int i=ks1*64;i<ks1*64+64;i++){
      float4 w = *(const float4*)&oW1[(size_t)i*HDIM+c1];
      f4fma(acc[0], agfl[0][i], w);
      f4fma(acc[1], agfl[1][i], w);
    }
    #pragma unroll
    for (int r=0;r<2;r++) *(float4*)&part[(ks1*2+r)*HDIM+c1]=acc[r];
  }
  __syncthreads();
  {
    int h=t&255, r=t>>8;
    float s=0.f;
    #pragma unroll
    for (int k=0;k<8;k++) s+=part[(k*2+r)*HDIM+h];
    hid[r][h] = fmaxf(s+ob1[h], 0.f);
  }
  __syncthreads();
  // ---- final stage2: (2 x 256) @ (256 x 128), row rr, 8-way h-split ----
  {
    float4 a2 = make_float4(0.f,0.f,0.f,0.f);
    #pragma unroll 8
    for (int h=ps*32;h<ps*32+32;h++){
      float4 w = *(const float4*)&oW2[(size_t)h*DD+c];
      f4fma(a2, hid[rr][h], w);
    }
    *(float4*)&part[(rr*8+ps)*DD+c]=a2;
  }
  __syncthreads();
  if (t<256){
    int cc=t&127, r=t>>7;
    float s=0.f;
    #pragma unroll
    for (int k=0;k<8;k++) s+=part[(r*8+k)*DD+cc];
    anew[(size_t)(n0+r)*DD+cc]=s+ob2[cc];
  }
}

extern "C" void kernel_launch(void* const* d_in, const int* in_sizes, int n_in,
                              void* d_out, int out_size, void* d_ws, size_t ws_size,
                              hipStream_t stream) {
  const float* af       = (const float*)d_in[0];
  const float* at       = (const float*)d_in[1];
  const float* pf       = (const float*)d_in[2];
  const float* Hm       = (const float*)d_in[3];
  const float* type_emb = (const float*)d_in[4];
  const float* w_W1 = (const float*)d_in[5];
  const float* w_b1 = (const float*)d_in[6];
  const float* w_W2 = (const float*)d_in[7];
  const float* w_b2 = (const float*)d_in[8];
  const float* d_W1 = (const float*)d_in[9];
  const float* d_b1 = (const float*)d_in[10];
  const float* d_W2 = (const float*)d_in[11];
  const float* d_b2 = (const float*)d_in[12];
  const float* f_W1 = (const float*)d_in[13];
  const float* f_b1 = (const float*)d_in[14];
  const float* f_W2 = (const float*)d_in[15];
  const float* f_b2 = (const float*)d_in[16];
  const float* o_W1 = (const float*)d_in[17];
  const float* o_b1 = (const float*)d_in[18];
  const float* o_W2 = (const float*)d_in[19];
  const float* o_b2 = (const float*)d_in[20];
  const float* q_W  = (const float*)d_in[21];
  const float* q_b  = (const float*)d_in[22];
  const float* k_W  = (const float*)d_in[23];
  const float* k_b  = (const float*)d_in[24];
  const float* v_W  = (const float*)d_in[25];
  const float* v_b  = (const float*)d_in[26];
  const float* iq_W = (const float*)d_in[27];
  const float* iq_b = (const float*)d_in[28];
  const float* ik_W = (const float*)d_in[29];
  const float* ik_b = (const float*)d_in[30];
  const float* iv_W = (const float*)d_in[31];
  const float* iv_b = (const float*)d_in[32];
  const float* op_W = (const float*)d_in[33];
  const float* op_b = (const float*)d_in[34];

  float* ws   = (float*)d_ws;
  float* out  = (float*)d_out;
  float* anew = out;                 // (B,N,D)
  float* pnew = out + BB*NN*DD;      // (B,N,D)

  prep_kernel<<<PB_END, 256, 0, stream>>>(
      ws+WS_G, ws+WS_C0, w_b1, w_W2, w_b2,
      Hm, af, at, w_W1, w_b1,
      ws+WS_U1, ws+WS_ETYPE, ws+WS_V,
      pf, k_W,k_b,ik_W,ik_b, v_W,v_b,iv_W,iv_b,
      ws+WS_K2, ws+WS_V2);
  edge_kernel<<<256,512,0,stream>>>(
      Hm, af, ws+WS_V, ws+WS_U1, ws+WS_ETYPE,
      w_W1, w_b1, w_W2, w_b2,
      d_W1,d_b1,d_W2,d_b2, f_W1,f_b1,f_W2,f_b2,
      type_emb, ws+WS_G, ws+WS_C0,
      ws+WS_EDGEF, ws+WS_ETE, ws+WS_HWT);
  agent_kernel<<<256,512,0,stream>>>(
      ws+WS_HWT, ws+WS_EDGEF, ws+WS_ETE, af,
      q_W, q_b, iq_W, iq_b,
      ws+WS_K2, ws+WS_V2, op_W, op_b,
      o_W1,o_b1,o_W2,o_b2, pnew, anew);
}